// Round 1
// baseline (9950.573 us; speedup 1.0000x reference)
//
#include <hip/hip_runtime.h>
#include <cstddef>

#define L_TOT 21504

// ============================ GEMM ============================
// C[M,N] = A op B[K,N] (+bias, optional relu)
// AMODE 0: A row-major (M,K)
// AMODE 1: A K-major (K,M)  (i.e. NCHW image, 1x1 conv)
// AMODE 2: implicit im2col of CHW image (Cin=K/9, 3x3 SAME), A = image
template<int AMODE, bool RELU>
__global__ __launch_bounds__(256) void gemm_k(
    const float* __restrict__ A, const float* __restrict__ B,
    const float* __restrict__ bias, float* __restrict__ C,
    int M, int N, int K, int H, int W)
{
    __shared__ float As[16][65];
    __shared__ float Bs[16][65];
    const int tid = threadIdx.x;
    const int m0 = blockIdx.y * 64, n0 = blockIdx.x * 64;
    const int tx = tid & 15, ty = tid >> 4;
    float acc[4][4] = {};

    for (int k0 = 0; k0 < K; k0 += 16) {
        if (AMODE == 0) {
            int k = tid & 15, m = tid >> 4;
#pragma unroll
            for (int i = 0; i < 4; ++i)
                As[k][m + i * 16] = A[(size_t)(m0 + m + i * 16) * K + (k0 + k)];
        } else if (AMODE == 1) {
            int ml = tid & 63, kl = tid >> 6;
#pragma unroll
            for (int i = 0; i < 4; ++i)
                As[kl + i * 4][ml] = A[(size_t)(k0 + kl + i * 4) * M + (m0 + ml)];
        } else {
            int ml = tid & 63, kl = tid >> 6;
#pragma unroll
            for (int i = 0; i < 4; ++i) {
                int kg = k0 + kl + i * 4;
                int c = kg / 9, q = kg % 9;
                int dy = q / 3 - 1, dx = q % 3 - 1;
                int m = m0 + ml;
                int yy = m / W + dy, xx = m % W + dx;
                float v = 0.f;
                if (yy >= 0 && yy < H && xx >= 0 && xx < W)
                    v = A[(size_t)c * H * W + (size_t)yy * W + xx];
                As[kl + i * 4][ml] = v;
            }
        }
        {
            int nl = tid & 63, kl = tid >> 6;
#pragma unroll
            for (int i = 0; i < 4; ++i) {
                int n = n0 + nl;
                Bs[kl + i * 4][nl] = (n < N) ? B[(size_t)(k0 + kl + i * 4) * N + n] : 0.f;
            }
        }
        __syncthreads();
#pragma unroll
        for (int kk = 0; kk < 16; ++kk) {
            float a[4], b[4];
#pragma unroll
            for (int i = 0; i < 4; ++i) a[i] = As[kk][ty * 4 + i];
#pragma unroll
            for (int j = 0; j < 4; ++j) b[j] = Bs[kk][tx * 4 + j];
#pragma unroll
            for (int i = 0; i < 4; ++i)
#pragma unroll
                for (int j = 0; j < 4; ++j)
                    acc[i][j] += a[i] * b[j];
        }
        __syncthreads();
    }
#pragma unroll
    for (int i = 0; i < 4; ++i) {
        int m = m0 + ty * 4 + i;
#pragma unroll
        for (int j = 0; j < 4; ++j) {
            int n = n0 + tx * 4 + j;
            if (n < N) {
                float v = acc[i][j] + (bias ? bias[n] : 0.f);
                if (RELU) v = fmaxf(v, 0.f);
                C[(size_t)m * N + n] = v;
            }
        }
    }
}

// ============================ elementwise add ============================
__global__ __launch_bounds__(256) void add_k(const float* __restrict__ a,
                                             const float* __restrict__ b,
                                             float* __restrict__ o, int n)
{
    int i = blockIdx.x * 256 + threadIdx.x;
    if (i < n) o[i] = a[i] + b[i];
}

// ============================ GroupNorm ============================
// stats[g*2] += sum, stats[g*2+1] += sumsq over group's 8 channels x P pixels
__global__ __launch_bounds__(256) void gn_stats_k(const float* __restrict__ X, int P,
                                                  float* __restrict__ stats)
{
    int g = blockIdx.x;
    size_t total = (size_t)P * 8;
    float a = 0.f, b = 0.f;
    size_t stride = (size_t)gridDim.y * 256;
    for (size_t idx = (size_t)blockIdx.y * 256 + threadIdx.x; idx < total; idx += stride) {
        size_t p = idx >> 3;
        int j = (int)(idx & 7);
        float v = X[p * 256 + g * 8 + j];
        a += v; b += v * v;
    }
#pragma unroll
    for (int o = 32; o > 0; o >>= 1) { a += __shfl_down(a, o, 64); b += __shfl_down(b, o, 64); }
    __shared__ float s1[4], s2[4];
    int lane = threadIdx.x & 63, w = threadIdx.x >> 6;
    if (lane == 0) { s1[w] = a; s2[w] = b; }
    __syncthreads();
    if (threadIdx.x == 0) {
        atomicAdd(&stats[g * 2 + 0], s1[0] + s1[1] + s1[2] + s1[3]);
        atomicAdd(&stats[g * 2 + 1], s2[0] + s2[1] + s2[2] + s2[3]);
    }
}

template<bool RELU>
__global__ __launch_bounds__(256) void gn_apply_k(float* __restrict__ X, int P,
                                                  const float* __restrict__ stats,
                                                  const float* __restrict__ gamma,
                                                  const float* __restrict__ beta)
{
    size_t i = (size_t)blockIdx.x * 256 + threadIdx.x;
    int c = (int)(i & 255), g = c >> 3;
    float cnt = (float)P * 8.f;
    float mean = stats[g * 2] / cnt;
    float var = stats[g * 2 + 1] / cnt - mean * mean;
    float v = (X[i] - mean) * rsqrtf(var + 1e-5f) * gamma[c] + beta[c];
    if (RELU) v = fmaxf(v, 0.f);
    X[i] = v;
}

// ============================ sine pos embed + level embed ============================
__global__ __launch_bounds__(256) void pos_embed_k(float* __restrict__ pos,
                                                   const float* __restrict__ level_embed)
{
    int l = blockIdx.x, d = threadIdx.x;
    int lvl, Wt, base;
    if (l < 1024)      { lvl = 0; Wt = 32;  base = 0; }
    else if (l < 5120) { lvl = 1; Wt = 64;  base = 1024; }
    else               { lvl = 2; Wt = 128; base = 5120; }
    int pp = l - base;
    int ty = pp / Wt, tx = pp % Wt;
    const float TWO_PI = 6.283185307179586f;
    float e = (d < 128) ? ((float)(ty + 1) * TWO_PI / ((float)Wt + 1e-6f))
                        : ((float)(tx + 1) * TWO_PI / ((float)Wt + 1e-6f));
    int k = d & 127;
    int m = k >> 1;
    float t = powf(10000.f, (float)m * (1.f / 64.f));
    float v = (k & 1) ? cosf(e / t) : sinf(e / t);
    pos[(size_t)l * 256 + d] = v + level_embed[lvl * 256 + d];
}

// ============================ softmax over 12 ============================
__global__ __launch_bounds__(256) void softmax12_k(float* __restrict__ w, int total)
{
    int i = blockIdx.x * 256 + threadIdx.x;
    if (i >= total) return;
    float* p = w + (size_t)i * 12;
    float m = p[0];
#pragma unroll
    for (int j = 1; j < 12; ++j) m = fmaxf(m, p[j]);
    float e[12];
    float s = 0.f;
#pragma unroll
    for (int j = 0; j < 12; ++j) { e[j] = expf(p[j] - m); s += e[j]; }
    float r = 1.f / s;
#pragma unroll
    for (int j = 0; j < 12; ++j) p[j] = e[j] * r;
}

// ============================ deformable sampling ============================
// block = token l; tid = h*32+d; value layout (L, 8, 32)
__global__ __launch_bounds__(256) void msdeform_k(
    const float* __restrict__ value, const float* __restrict__ offs,
    const float* __restrict__ attw, float* __restrict__ out)
{
    int l = blockIdx.x;
    int tid = threadIdx.x;
    int h = tid >> 5, d = tid & 31;
    int Wt, base;
    if (l < 1024)      { Wt = 32;  base = 0; }
    else if (l < 5120) { Wt = 64;  base = 1024; }
    else               { Wt = 128; base = 5120; }
    int pp = l - base;
    int tyy = pp / Wt, txx = pp % Wt;
    float refx = ((float)txx + 0.5f) / (float)Wt;
    float refy = ((float)tyy + 0.5f) / (float)Wt;

    const float* offs_l = offs + (size_t)l * 192 + h * 24;
    const float* attw_l = attw + (size_t)l * 96 + h * 12;
    float acc = 0.f;
#pragma unroll
    for (int lvl = 0; lvl < 3; ++lvl) {
        int Ws = 32 << lvl;
        int start = (lvl == 0) ? 0 : (lvl == 1 ? 1024 : 5120);
        float invW = 1.f / (float)Ws;
#pragma unroll
        for (int p = 0; p < 4; ++p) {
            float ox = offs_l[lvl * 8 + p * 2 + 0];
            float oy = offs_l[lvl * 8 + p * 2 + 1];
            float wgt = attw_l[lvl * 4 + p];
            float gx = (refx + ox * invW) * (float)Ws - 0.5f;
            float gy = (refy + oy * invW) * (float)Ws - 0.5f;
            float x0f = floorf(gx), y0f = floorf(gy);
            float fx = gx - x0f, fy = gy - y0f;
            int x0 = (int)x0f, y0 = (int)y0f;
            float v00 = 0.f, v10 = 0.f, v01 = 0.f, v11 = 0.f;
            if ((unsigned)x0 < (unsigned)Ws && (unsigned)y0 < (unsigned)Ws)
                v00 = value[((size_t)(start + y0 * Ws + x0)) * 256 + h * 32 + d];
            if ((unsigned)(x0 + 1) < (unsigned)Ws && (unsigned)y0 < (unsigned)Ws)
                v10 = value[((size_t)(start + y0 * Ws + x0 + 1)) * 256 + h * 32 + d];
            if ((unsigned)x0 < (unsigned)Ws && (unsigned)(y0 + 1) < (unsigned)Ws)
                v01 = value[((size_t)(start + (y0 + 1) * Ws + x0)) * 256 + h * 32 + d];
            if ((unsigned)(x0 + 1) < (unsigned)Ws && (unsigned)(y0 + 1) < (unsigned)Ws)
                v11 = value[((size_t)(start + (y0 + 1) * Ws + x0 + 1)) * 256 + h * 32 + d];
            float s = v00 * (1.f - fx) * (1.f - fy) + v10 * fx * (1.f - fy)
                    + v01 * (1.f - fx) * fy + v11 * fx * fy;
            acc += wgt * s;
        }
    }
    out[(size_t)l * 256 + tid] = acc;
}

// ============================ residual + LayerNorm (in-place on src) ============================
__global__ __launch_bounds__(256) void resid_ln_k(
    float* __restrict__ src, const float* __restrict__ r,
    const float* __restrict__ g, const float* __restrict__ b)
{
    int l = blockIdx.x, tid = threadIdx.x;
    float v = src[(size_t)l * 256 + tid] + r[(size_t)l * 256 + tid];
    float a = v, s2 = v * v;
#pragma unroll
    for (int o = 32; o > 0; o >>= 1) { a += __shfl_down(a, o, 64); s2 += __shfl_down(s2, o, 64); }
    __shared__ float sh1[4], sh2[4], res[2];
    int lane = tid & 63, w = tid >> 6;
    if (lane == 0) { sh1[w] = a; sh2[w] = s2; }
    __syncthreads();
    if (tid == 0) {
        float A = sh1[0] + sh1[1] + sh1[2] + sh1[3];
        float B = sh2[0] + sh2[1] + sh2[2] + sh2[3];
        float mu = A * (1.f / 256.f);
        res[0] = mu;
        res[1] = rsqrtf(B * (1.f / 256.f) - mu * mu + 1e-5f);
    }
    __syncthreads();
    src[(size_t)l * 256 + tid] = (v - res[0]) * res[1] * g[tid] + b[tid];
}

// ============================ bilinear 2x upsample (128->256) + add ============================
__global__ __launch_bounds__(256) void upsample_add_k(
    float* __restrict__ lat, const float* __restrict__ src2)
{
    int p = blockIdx.x;          // 0..65535 output pixel
    int d = threadIdx.x;
    int y = p >> 8, x = p & 255;
    float yin = (float)y * 0.5f - 0.25f;
    float xin = (float)x * 0.5f - 0.25f;
    float y0f = floorf(yin), x0f = floorf(xin);
    float fy = yin - y0f, fx = xin - x0f;
    int y0 = (int)y0f, x0 = (int)x0f;
    int y0c = min(max(y0, 0), 127), y1c = min(max(y0 + 1, 0), 127);
    int x0c = min(max(x0, 0), 127), x1c = min(max(x0 + 1, 0), 127);
    float v00 = src2[((size_t)(y0c * 128 + x0c)) * 256 + d];
    float v10 = src2[((size_t)(y0c * 128 + x1c)) * 256 + d];
    float v01 = src2[((size_t)(y1c * 128 + x0c)) * 256 + d];
    float v11 = src2[((size_t)(y1c * 128 + x1c)) * 256 + d];
    float v = v00 * (1.f - fx) * (1.f - fy) + v10 * fx * (1.f - fy)
            + v01 * (1.f - fx) * fy + v11 * fx * fy;
    lat[(size_t)p * 256 + d] += v;
}

// ============================ transpose (P,256) -> (256,P) ============================
__global__ __launch_bounds__(256) void transpose_k(const float* __restrict__ in,
                                                   float* __restrict__ out, int P)
{
    __shared__ float t[32][33];
    int p0 = blockIdx.x * 32, c0 = blockIdx.y * 32;
    int x = threadIdx.x & 31, y = threadIdx.x >> 5;
#pragma unroll
    for (int i = 0; i < 4; ++i) {
        int r = y + i * 8;
        t[r][x] = in[(size_t)(p0 + r) * 256 + c0 + x];
    }
    __syncthreads();
#pragma unroll
    for (int i = 0; i < 4; ++i) {
        int r = y + i * 8;
        out[(size_t)(c0 + r) * P + p0 + x] = t[x][r];
    }
}

// ============================ conv weight transpose OIHW(256,2304) -> (2304,256) ============================
__global__ __launch_bounds__(256) void transpose_w_k(const float* __restrict__ w,
                                                     float* __restrict__ wt)
{
    int idx = blockIdx.x * 256 + threadIdx.x;
    if (idx >= 2304 * 256) return;
    int o = idx / 2304, k = idx % 2304;
    wt[(size_t)k * 256 + o] = w[idx];
}

// ============================ host launcher ============================
extern "C" void kernel_launch(void* const* d_in, const int* in_sizes, int n_in,
                              void* d_out, int out_size, void* d_ws, size_t ws_size,
                              hipStream_t stream) {
    const float* res2    = (const float*)d_in[0];
    const float* res3    = (const float*)d_in[1];
    const float* res4    = (const float*)d_in[2];
    const float* res5    = (const float*)d_in[3];
    const float* proj_w5 = (const float*)d_in[4];
    const float* proj_b5 = (const float*)d_in[5];
    const float* gn_g5   = (const float*)d_in[6];
    const float* gn_b5   = (const float*)d_in[7];
    const float* proj_w4 = (const float*)d_in[8];
    const float* proj_b4 = (const float*)d_in[9];
    const float* gn_g4   = (const float*)d_in[10];
    const float* gn_b4   = (const float*)d_in[11];
    const float* proj_w3 = (const float*)d_in[12];
    const float* proj_b3 = (const float*)d_in[13];
    const float* gn_g3   = (const float*)d_in[14];
    const float* gn_b3   = (const float*)d_in[15];
    const float* level_embed = (const float*)d_in[16];
    const float* enc_vw  = (const float*)d_in[17];
    const float* enc_vb  = (const float*)d_in[18];
    const float* enc_ow  = (const float*)d_in[19];
    const float* enc_ob  = (const float*)d_in[20];
    const float* enc_aw  = (const float*)d_in[21];
    const float* enc_ab  = (const float*)d_in[22];
    const float* enc_pw  = (const float*)d_in[23];
    const float* enc_pb  = (const float*)d_in[24];
    const float* enc_ln1g = (const float*)d_in[25];
    const float* enc_ln1b = (const float*)d_in[26];
    const float* enc_f1w = (const float*)d_in[27];
    const float* enc_f1b = (const float*)d_in[28];
    const float* enc_f2w = (const float*)d_in[29];
    const float* enc_f2b = (const float*)d_in[30];
    const float* enc_ln2g = (const float*)d_in[31];
    const float* enc_ln2b = (const float*)d_in[32];
    const float* lat_w   = (const float*)d_in[33];
    const float* lat_gn_g = (const float*)d_in[34];
    const float* lat_gn_b = (const float*)d_in[35];
    const float* out_w   = (const float*)d_in[36];
    const float* out_gn_g = (const float*)d_in[37];
    const float* out_gn_b = (const float*)d_in[38];
    const float* mask_w  = (const float*)d_in[39];
    const float* mask_b  = (const float*)d_in[40];

    float* ws = (float*)d_ws;
    const int L = L_TOT;
    // workspace layout (floats)
    float* src   = ws;                       // 5,505,024
    float* pos   = ws + 5505024;             // 5,505,024
    float* qbuf  = ws + 11010048;            // 5,505,024
    float* value = ws + 16515072;            // 5,505,024
    float* msout = ws + 22020096;            // 5,505,024
    float* offs  = ws + 27525120;            // 4,128,768
    float* attw  = ws + 31653888;            // 2,064,384
    float* ffnh  = ws + 33718272;            // 22,020,096
    float* wt0   = ws + 55738368;            // 589,824
    float* wt1   = ws + 56328192;            // 589,824
    float* stats = ws + 56918016;            // 320 (5 slots x 64)
    // tail aliases (encoder scratch is dead by then; src stays live)
    float* big0  = pos;                      // 16,777,216
    float* big1  = pos + 16777216;           // 16,777,216

    hipMemsetAsync(stats, 0, 320 * sizeof(float), stream);

    dim3 blk(256);

    // ---- level projections (1x1 conv GEMMs, K-major A) + GroupNorm ----
    gemm_k<1, false><<<dim3(4, 1024 / 64), blk, 0, stream>>>(res5, proj_w5, proj_b5, src, 1024, 256, 2048, 0, 0);
    gemm_k<1, false><<<dim3(4, 4096 / 64), blk, 0, stream>>>(res4, proj_w4, proj_b4, src + (size_t)1024 * 256, 4096, 256, 1024, 0, 0);
    gemm_k<1, false><<<dim3(4, 16384 / 64), blk, 0, stream>>>(res3, proj_w3, proj_b3, src + (size_t)5120 * 256, 16384, 256, 512, 0, 0);

    gn_stats_k<<<dim3(32, 4), blk, 0, stream>>>(src, 1024, stats + 0);
    gn_stats_k<<<dim3(32, 8), blk, 0, stream>>>(src + (size_t)1024 * 256, 4096, stats + 64);
    gn_stats_k<<<dim3(32, 16), blk, 0, stream>>>(src + (size_t)5120 * 256, 16384, stats + 128);
    gn_apply_k<false><<<1024, blk, 0, stream>>>(src, 1024, stats + 0, gn_g5, gn_b5);
    gn_apply_k<false><<<4096, blk, 0, stream>>>(src + (size_t)1024 * 256, 4096, stats + 64, gn_g4, gn_b4);
    gn_apply_k<false><<<16384, blk, 0, stream>>>(src + (size_t)5120 * 256, 16384, stats + 128, gn_g3, gn_b3);

    // ---- positional embedding ----
    pos_embed_k<<<L, blk, 0, stream>>>(pos, level_embed);

    // ---- encoder layers ----
    for (int i = 0; i < 6; ++i) {
        const float* vw = enc_vw + (size_t)i * 65536;
        const float* vb = enc_vb + (size_t)i * 256;
        const float* ow = enc_ow + (size_t)i * 49152;
        const float* ob = enc_ob + (size_t)i * 192;
        const float* aw = enc_aw + (size_t)i * 24576;
        const float* ab = enc_ab + (size_t)i * 96;
        const float* pw = enc_pw + (size_t)i * 65536;
        const float* pb = enc_pb + (size_t)i * 256;
        const float* l1g = enc_ln1g + (size_t)i * 256;
        const float* l1b = enc_ln1b + (size_t)i * 256;
        const float* f1w = enc_f1w + (size_t)i * 262144;
        const float* f1b = enc_f1b + (size_t)i * 1024;
        const float* f2w = enc_f2w + (size_t)i * 262144;
        const float* f2b = enc_f2b + (size_t)i * 256;
        const float* l2g = enc_ln2g + (size_t)i * 256;
        const float* l2b = enc_ln2b + (size_t)i * 256;

        add_k<<<(L * 256) / 256, blk, 0, stream>>>(src, pos, qbuf, L * 256);
        gemm_k<0, false><<<dim3(4, 336), blk, 0, stream>>>(src, vw, vb, value, L, 256, 256, 0, 0);
        gemm_k<0, false><<<dim3(3, 336), blk, 0, stream>>>(qbuf, ow, ob, offs, L, 192, 256, 0, 0);
        gemm_k<0, false><<<dim3(2, 336), blk, 0, stream>>>(qbuf, aw, ab, attw, L, 96, 256, 0, 0);
        softmax12_k<<<(L * 8 + 255) / 256, blk, 0, stream>>>(attw, L * 8);
        msdeform_k<<<L, blk, 0, stream>>>(value, offs, attw, msout);
        gemm_k<0, false><<<dim3(4, 336), blk, 0, stream>>>(msout, pw, pb, qbuf, L, 256, 256, 0, 0);
        resid_ln_k<<<L, blk, 0, stream>>>(src, qbuf, l1g, l1b);
        gemm_k<0, true><<<dim3(16, 336), blk, 0, stream>>>(src, f1w, f1b, ffnh, L, 1024, 256, 0, 0);
        gemm_k<0, false><<<dim3(4, 336), blk, 0, stream>>>(ffnh, f2w, f2b, qbuf, L, 256, 1024, 0, 0);
        resid_ln_k<<<L, blk, 0, stream>>>(src, qbuf, l2g, l2b);
    }

    // ---- decoder tail ----
    transpose_w_k<<<(2304 * 256) / 256, blk, 0, stream>>>(out_w, wt0);
    transpose_w_k<<<(2304 * 256) / 256, blk, 0, stream>>>(mask_w, wt1);

    // lat = GN(res2 @ lat_w)   (token-major in big0)
    gemm_k<1, false><<<dim3(4, 1024), blk, 0, stream>>>(res2, lat_w, nullptr, big0, 65536, 256, 256, 0, 0);
    gn_stats_k<<<dim3(32, 32), blk, 0, stream>>>(big0, 65536, stats + 192);
    gn_apply_k<false><<<65536, blk, 0, stream>>>(big0, 65536, stats + 192, lat_gn_g, lat_gn_b);

    // += bilinear 2x upsample of encoder level-2 output
    upsample_add_k<<<65536, blk, 0, stream>>>(big0, src + (size_t)5120 * 256);

    // transpose to CHW, conv3x3 (out_w), GN+relu, transpose, conv3x3 (mask_w)+bias, to d_out
    transpose_k<<<dim3(2048, 8), blk, 0, stream>>>(big0, big1, 65536);
    gemm_k<2, false><<<dim3(4, 1024), blk, 0, stream>>>(big1, wt0, nullptr, big0, 65536, 256, 2304, 256, 256);
    gn_stats_k<<<dim3(32, 32), blk, 0, stream>>>(big0, 65536, stats + 256);
    gn_apply_k<true><<<65536, blk, 0, stream>>>(big0, 65536, stats + 256, out_gn_g, out_gn_b);
    transpose_k<<<dim3(2048, 8), blk, 0, stream>>>(big0, big1, 65536);
    gemm_k<2, false><<<dim3(4, 1024), blk, 0, stream>>>(big1, wt1, mask_b, big0, 65536, 256, 2304, 256, 256);
    transpose_k<<<dim3(2048, 8), blk, 0, stream>>>(big0, (float*)d_out, 65536);
}

// Round 2
// 3877.957 us; speedup vs baseline: 2.5659x; 2.5659x over previous
//
#include <hip/hip_runtime.h>
#include <cstddef>

#define L_TOT 21504

typedef __bf16 bf16_t;
typedef bf16_t bf16x8 __attribute__((ext_vector_type(8)));
typedef float floatx4 __attribute__((ext_vector_type(4)));

__device__ __forceinline__ bf16x8 bf8_zero() {
    bf16x8 v;
#pragma unroll
    for (int i = 0; i < 8; ++i) v[i] = (bf16_t)0.f;
    return v;
}

// ============================ MFMA GEMM ============================
// C[M,N] = A[M,K] (bf16 row-major) x Bt[N,K]^T (bf16, N-major) + bias
// AMODE 0: A row-major bf16
// AMODE 2: implicit im2col of bf16 CHW image (Cin=K/9, 3x3 SAME, H=W=256)
// Tiles: BM=128, BN=128, BK=32. 256 threads = 4 waves, each wave 64x64 (4x4 frags).
template<int AMODE, bool NBOUND, bool RELU, bool WF32, bool WBF>
__global__ __launch_bounds__(256) void gemm_bf_k(
    const bf16_t* __restrict__ A, const bf16_t* __restrict__ Bt,
    const float* __restrict__ bias, float* __restrict__ C, bf16_t* __restrict__ Cb,
    int M, int N, int K)
{
    __shared__ bf16_t As[128][40];
    __shared__ bf16_t Bs[128][40];
    const int tid = threadIdx.x;
    const int m0 = blockIdx.y * 128, n0 = blockIdx.x * 128;
    const int lane = tid & 63, wv = tid >> 6;
    const int ln16 = lane & 15, quad = lane >> 4;
    const int wm = (wv >> 1) * 64, wn = (wv & 1) * 64;

    floatx4 acc[4][4];
#pragma unroll
    for (int i = 0; i < 4; ++i)
#pragma unroll
        for (int j = 0; j < 4; ++j)
            acc[i][j] = (floatx4){0.f, 0.f, 0.f, 0.f};

    const int srow = tid >> 2;          // 0..63
    const int sseg = (tid & 3) * 8;     // 0,8,16,24
    // im2col staging coords
    const int irow = tid >> 1;          // 0..127
    const int ikb  = (tid & 1) * 16;
    const int im   = m0 + irow;
    const int iy   = im >> 8, ix = im & 255;

    for (int k0 = 0; k0 < K; k0 += 32) {
        if (AMODE == 0) {
#pragma unroll
            for (int p = 0; p < 2; ++p) {
                int r = srow + p * 64;
                *(bf16x8*)&As[r][sseg] =
                    *(const bf16x8*)&A[(size_t)(m0 + r) * K + k0 + sseg];
            }
        } else {
#pragma unroll
            for (int e = 0; e < 16; ++e) {
                int kg = k0 + ikb + e;
                int c = kg / 9, q = kg - c * 9;
                int yy = iy + q / 3 - 1, xx = ix + (q % 3) - 1;
                bf16_t v = (bf16_t)0.f;
                if ((unsigned)yy < 256u && (unsigned)xx < 256u)
                    v = A[((size_t)c << 16) + (yy << 8) + xx];
                As[irow][ikb + e] = v;
            }
        }
#pragma unroll
        for (int p = 0; p < 2; ++p) {
            int r = srow + p * 64;
            bf16x8 bv;
            if (!NBOUND || (n0 + r) < N)
                bv = *(const bf16x8*)&Bt[(size_t)(n0 + r) * K + k0 + sseg];
            else
                bv = bf8_zero();
            *(bf16x8*)&Bs[r][sseg] = bv;
        }
        __syncthreads();

        bf16x8 af[4], bfv[4];
#pragma unroll
        for (int i = 0; i < 4; ++i)
            af[i] = *(const bf16x8*)&As[wm + i * 16 + ln16][quad * 8];
#pragma unroll
        for (int j = 0; j < 4; ++j)
            bfv[j] = *(const bf16x8*)&Bs[wn + j * 16 + ln16][quad * 8];
#pragma unroll
        for (int i = 0; i < 4; ++i)
#pragma unroll
            for (int j = 0; j < 4; ++j)
                acc[i][j] = __builtin_amdgcn_mfma_f32_16x16x32_bf16(
                    af[i], bfv[j], acc[i][j], 0, 0, 0);
        __syncthreads();
    }

#pragma unroll
    for (int i = 0; i < 4; ++i) {
        int rbase = m0 + wm + i * 16 + quad * 4;
#pragma unroll
        for (int j = 0; j < 4; ++j) {
            int col = n0 + wn + j * 16 + ln16;
            if (NBOUND && col >= N) continue;
            float bv = bias ? bias[col] : 0.f;
#pragma unroll
            for (int r = 0; r < 4; ++r) {
                float v = acc[i][j][r] + bv;
                if (RELU) v = fmaxf(v, 0.f);
                size_t idx = (size_t)(rbase + r) * N + col;
                if (WF32) C[idx] = v;
                if (WBF)  Cb[idx] = (bf16_t)v;
            }
        }
    }
}

// ============================ transpose-convert f32 [R][C] -> bf16 [C][R] ============================
__global__ __launch_bounds__(256) void tconv_k(const float* __restrict__ in,
                                               bf16_t* __restrict__ out,
                                               int R, int Ccols,
                                               size_t in_ls, size_t out_ls)
{
    const float* ip = in + (size_t)blockIdx.z * in_ls;
    bf16_t* op = out + (size_t)blockIdx.z * out_ls;
    __shared__ float t[32][33];
    int r0 = blockIdx.y * 32, c0 = blockIdx.x * 32;
    int x = threadIdx.x & 31, y8 = threadIdx.x >> 5;
#pragma unroll
    for (int i = 0; i < 4; ++i) {
        int r = y8 + i * 8;
        t[r][x] = ip[(size_t)(r0 + r) * Ccols + c0 + x];
    }
    __syncthreads();
#pragma unroll
    for (int i = 0; i < 4; ++i) {
        int r = y8 + i * 8;
        op[(size_t)(c0 + r) * R + r0 + x] = (bf16_t)t[x][r];
    }
}

// ============================ elementwise f32 -> bf16 ============================
__global__ __launch_bounds__(256) void cvt_k(const float* __restrict__ in,
                                             bf16_t* __restrict__ out, int n)
{
    int i = blockIdx.x * 256 + threadIdx.x;
    if (i < n) out[i] = (bf16_t)in[i];
}

// ============================ add -> bf16 ============================
__global__ __launch_bounds__(256) void add_k(const float* __restrict__ a,
                                             const float* __restrict__ b,
                                             bf16_t* __restrict__ o, int n)
{
    int i = blockIdx.x * 256 + threadIdx.x;
    if (i < n) o[i] = (bf16_t)(a[i] + b[i]);
}

// ============================ GroupNorm ============================
__global__ __launch_bounds__(256) void gn_stats_k(const float* __restrict__ X, int P,
                                                  float* __restrict__ stats)
{
    int g = blockIdx.x;
    size_t total = (size_t)P * 8;
    float a = 0.f, b = 0.f;
    size_t stride = (size_t)gridDim.y * 256;
    for (size_t idx = (size_t)blockIdx.y * 256 + threadIdx.x; idx < total; idx += stride) {
        size_t p = idx >> 3;
        int j = (int)(idx & 7);
        float v = X[p * 256 + g * 8 + j];
        a += v; b += v * v;
    }
#pragma unroll
    for (int o = 32; o > 0; o >>= 1) { a += __shfl_down(a, o, 64); b += __shfl_down(b, o, 64); }
    __shared__ float s1[4], s2[4];
    int lane = threadIdx.x & 63, w = threadIdx.x >> 6;
    if (lane == 0) { s1[w] = a; s2[w] = b; }
    __syncthreads();
    if (threadIdx.x == 0) {
        atomicAdd(&stats[g * 2 + 0], s1[0] + s1[1] + s1[2] + s1[3]);
        atomicAdd(&stats[g * 2 + 1], s2[0] + s2[1] + s2[2] + s2[3]);
    }
}

template<bool RELU>
__global__ __launch_bounds__(256) void gn_apply_k(float* __restrict__ X, int P,
                                                  const float* __restrict__ stats,
                                                  const float* __restrict__ gamma,
                                                  const float* __restrict__ beta)
{
    size_t i = (size_t)blockIdx.x * 256 + threadIdx.x;
    int c = (int)(i & 255), g = c >> 3;
    float cnt = (float)P * 8.f;
    float mean = stats[g * 2] / cnt;
    float var = stats[g * 2 + 1] / cnt - mean * mean;
    float v = (X[i] - mean) * rsqrtf(var + 1e-5f) * gamma[c] + beta[c];
    if (RELU) v = fmaxf(v, 0.f);
    X[i] = v;
}

// ============================ sine pos embed + level embed ============================
__global__ __launch_bounds__(256) void pos_embed_k(float* __restrict__ pos,
                                                   const float* __restrict__ level_embed)
{
    int l = blockIdx.x, d = threadIdx.x;
    int lvl, Wt, base;
    if (l < 1024)      { lvl = 0; Wt = 32;  base = 0; }
    else if (l < 5120) { lvl = 1; Wt = 64;  base = 1024; }
    else               { lvl = 2; Wt = 128; base = 5120; }
    int pp = l - base;
    int ty = pp / Wt, tx = pp % Wt;
    const float TWO_PI = 6.283185307179586f;
    float e = (d < 128) ? ((float)(ty + 1) * TWO_PI / ((float)Wt + 1e-6f))
                        : ((float)(tx + 1) * TWO_PI / ((float)Wt + 1e-6f));
    int k = d & 127;
    int m = k >> 1;
    float t = powf(10000.f, (float)m * (1.f / 64.f));
    float v = (k & 1) ? cosf(e / t) : sinf(e / t);
    pos[(size_t)l * 256 + d] = v + level_embed[lvl * 256 + d];
}

// ============================ softmax over 12 ============================
__global__ __launch_bounds__(256) void softmax12_k(float* __restrict__ w, int total)
{
    int i = blockIdx.x * 256 + threadIdx.x;
    if (i >= total) return;
    float* p = w + (size_t)i * 12;
    float m = p[0];
#pragma unroll
    for (int j = 1; j < 12; ++j) m = fmaxf(m, p[j]);
    float e[12];
    float s = 0.f;
#pragma unroll
    for (int j = 0; j < 12; ++j) { e[j] = expf(p[j] - m); s += e[j]; }
    float r = 1.f / s;
#pragma unroll
    for (int j = 0; j < 12; ++j) p[j] = e[j] * r;
}

// ============================ deformable sampling (out: bf16) ============================
__global__ __launch_bounds__(256) void msdeform_k(
    const float* __restrict__ value, const float* __restrict__ offs,
    const float* __restrict__ attw, bf16_t* __restrict__ out)
{
    int l = blockIdx.x;
    int tid = threadIdx.x;
    int h = tid >> 5, d = tid & 31;
    int Wt, base;
    if (l < 1024)      { Wt = 32;  base = 0; }
    else if (l < 5120) { Wt = 64;  base = 1024; }
    else               { Wt = 128; base = 5120; }
    int pp = l - base;
    int tyy = pp / Wt, txx = pp % Wt;
    float refx = ((float)txx + 0.5f) / (float)Wt;
    float refy = ((float)tyy + 0.5f) / (float)Wt;

    const float* offs_l = offs + (size_t)l * 192 + h * 24;
    const float* attw_l = attw + (size_t)l * 96 + h * 12;
    float acc = 0.f;
#pragma unroll
    for (int lvl = 0; lvl < 3; ++lvl) {
        int Ws = 32 << lvl;
        int start = (lvl == 0) ? 0 : (lvl == 1 ? 1024 : 5120);
        float invW = 1.f / (float)Ws;
#pragma unroll
        for (int p = 0; p < 4; ++p) {
            float ox = offs_l[lvl * 8 + p * 2 + 0];
            float oy = offs_l[lvl * 8 + p * 2 + 1];
            float wgt = attw_l[lvl * 4 + p];
            float gx = (refx + ox * invW) * (float)Ws - 0.5f;
            float gy = (refy + oy * invW) * (float)Ws - 0.5f;
            float x0f = floorf(gx), y0f = floorf(gy);
            float fx = gx - x0f, fy = gy - y0f;
            int x0 = (int)x0f, y0 = (int)y0f;
            float v00 = 0.f, v10 = 0.f, v01 = 0.f, v11 = 0.f;
            if ((unsigned)x0 < (unsigned)Ws && (unsigned)y0 < (unsigned)Ws)
                v00 = value[((size_t)(start + y0 * Ws + x0)) * 256 + h * 32 + d];
            if ((unsigned)(x0 + 1) < (unsigned)Ws && (unsigned)y0 < (unsigned)Ws)
                v10 = value[((size_t)(start + y0 * Ws + x0 + 1)) * 256 + h * 32 + d];
            if ((unsigned)x0 < (unsigned)Ws && (unsigned)(y0 + 1) < (unsigned)Ws)
                v01 = value[((size_t)(start + (y0 + 1) * Ws + x0)) * 256 + h * 32 + d];
            if ((unsigned)(x0 + 1) < (unsigned)Ws && (unsigned)(y0 + 1) < (unsigned)Ws)
                v11 = value[((size_t)(start + (y0 + 1) * Ws + x0 + 1)) * 256 + h * 32 + d];
            float s = v00 * (1.f - fx) * (1.f - fy) + v10 * fx * (1.f - fy)
                    + v01 * (1.f - fx) * fy + v11 * fx * fy;
            acc += wgt * s;
        }
    }
    out[(size_t)l * 256 + tid] = (bf16_t)acc;
}

// ============================ residual + LayerNorm (dual f32 + bf16 out) ============================
__global__ __launch_bounds__(256) void resid_ln_k(
    float* __restrict__ src, const float* __restrict__ r,
    const float* __restrict__ g, const float* __restrict__ b,
    bf16_t* __restrict__ src_bf)
{
    int l = blockIdx.x, tid = threadIdx.x;
    float v = src[(size_t)l * 256 + tid] + r[(size_t)l * 256 + tid];
    float a = v, s2 = v * v;
#pragma unroll
    for (int o = 32; o > 0; o >>= 1) { a += __shfl_down(a, o, 64); s2 += __shfl_down(s2, o, 64); }
    __shared__ float sh1[4], sh2[4], res[2];
    int lane = tid & 63, w = tid >> 6;
    if (lane == 0) { sh1[w] = a; sh2[w] = s2; }
    __syncthreads();
    if (tid == 0) {
        float A = sh1[0] + sh1[1] + sh1[2] + sh1[3];
        float B = sh2[0] + sh2[1] + sh2[2] + sh2[3];
        float mu = A * (1.f / 256.f);
        res[0] = mu;
        res[1] = rsqrtf(B * (1.f / 256.f) - mu * mu + 1e-5f);
    }
    __syncthreads();
    float o = (v - res[0]) * res[1] * g[tid] + b[tid];
    src[(size_t)l * 256 + tid] = o;
    src_bf[(size_t)l * 256 + tid] = (bf16_t)o;
}

// ============================ bilinear 2x upsample (128->256) + add ============================
__global__ __launch_bounds__(256) void upsample_add_k(
    float* __restrict__ lat, const float* __restrict__ src2)
{
    int p = blockIdx.x;
    int d = threadIdx.x;
    int y = p >> 8, x = p & 255;
    float yin = (float)y * 0.5f - 0.25f;
    float xin = (float)x * 0.5f - 0.25f;
    float y0f = floorf(yin), x0f = floorf(xin);
    float fy = yin - y0f, fx = xin - x0f;
    int y0 = (int)y0f, x0 = (int)x0f;
    int y0c = min(max(y0, 0), 127), y1c = min(max(y0 + 1, 0), 127);
    int x0c = min(max(x0, 0), 127), x1c = min(max(x0 + 1, 0), 127);
    float v00 = src2[((size_t)(y0c * 128 + x0c)) * 256 + d];
    float v10 = src2[((size_t)(y0c * 128 + x1c)) * 256 + d];
    float v01 = src2[((size_t)(y1c * 128 + x0c)) * 256 + d];
    float v11 = src2[((size_t)(y1c * 128 + x1c)) * 256 + d];
    float v = v00 * (1.f - fx) * (1.f - fy) + v10 * fx * (1.f - fy)
            + v01 * (1.f - fx) * fy + v11 * fx * fy;
    lat[(size_t)p * 256 + d] += v;
}

// ============================ transpose f32 (P,256) -> (256,P) ============================
__global__ __launch_bounds__(256) void transpose_k(const float* __restrict__ in,
                                                   float* __restrict__ out, int P)
{
    __shared__ float t[32][33];
    int p0 = blockIdx.x * 32, c0 = blockIdx.y * 32;
    int x = threadIdx.x & 31, y = threadIdx.x >> 5;
#pragma unroll
    for (int i = 0; i < 4; ++i) {
        int r = y + i * 8;
        t[r][x] = in[(size_t)(p0 + r) * 256 + c0 + x];
    }
    __syncthreads();
#pragma unroll
    for (int i = 0; i < 4; ++i) {
        int r = y + i * 8;
        out[(size_t)(c0 + r) * P + p0 + x] = t[x][r];
    }
}

// ============================ host launcher ============================
extern "C" void kernel_launch(void* const* d_in, const int* in_sizes, int n_in,
                              void* d_out, int out_size, void* d_ws, size_t ws_size,
                              hipStream_t stream) {
    const float* res2    = (const float*)d_in[0];
    const float* res3    = (const float*)d_in[1];
    const float* res4    = (const float*)d_in[2];
    const float* res5    = (const float*)d_in[3];
    const float* proj_w5 = (const float*)d_in[4];
    const float* proj_b5 = (const float*)d_in[5];
    const float* gn_g5   = (const float*)d_in[6];
    const float* gn_b5   = (const float*)d_in[7];
    const float* proj_w4 = (const float*)d_in[8];
    const float* proj_b4 = (const float*)d_in[9];
    const float* gn_g4   = (const float*)d_in[10];
    const float* gn_b4   = (const float*)d_in[11];
    const float* proj_w3 = (const float*)d_in[12];
    const float* proj_b3 = (const float*)d_in[13];
    const float* gn_g3   = (const float*)d_in[14];
    const float* gn_b3   = (const float*)d_in[15];
    const float* level_embed = (const float*)d_in[16];
    const float* enc_vw  = (const float*)d_in[17];
    const float* enc_vb  = (const float*)d_in[18];
    const float* enc_ow  = (const float*)d_in[19];
    const float* enc_ob  = (const float*)d_in[20];
    const float* enc_aw  = (const float*)d_in[21];
    const float* enc_ab  = (const float*)d_in[22];
    const float* enc_pw  = (const float*)d_in[23];
    const float* enc_pb  = (const float*)d_in[24];
    const float* enc_ln1g = (const float*)d_in[25];
    const float* enc_ln1b = (const float*)d_in[26];
    const float* enc_f1w = (const float*)d_in[27];
    const float* enc_f1b = (const float*)d_in[28];
    const float* enc_f2w = (const float*)d_in[29];
    const float* enc_f2b = (const float*)d_in[30];
    const float* enc_ln2g = (const float*)d_in[31];
    const float* enc_ln2b = (const float*)d_in[32];
    const float* lat_w   = (const float*)d_in[33];
    const float* lat_gn_g = (const float*)d_in[34];
    const float* lat_gn_b = (const float*)d_in[35];
    const float* out_w   = (const float*)d_in[36];
    const float* out_gn_g = (const float*)d_in[37];
    const float* out_gn_b = (const float*)d_in[38];
    const float* mask_w  = (const float*)d_in[39];
    const float* mask_b  = (const float*)d_in[40];

    char* wsb = (char*)d_ws;
    const int L = L_TOT;

    // ---- workspace layout (bytes) ----
    const size_t OFF_SRC   = 0;                  // f32 L*256         22,020,096
    const size_t OFF_POS   = 22020096;           // f32 L*256
    const size_t OFF_VALUE = 44040192;           // f32 L*256
    const size_t OFF_OFFS  = 66060288;           // f32 L*192         16,515,072
    const size_t OFF_ATTW  = 82575360;           // f32 L*96           8,257,536
    const size_t OFF_FFNH  = 90832896;           // bf16 L*1024       44,040,192
    const size_t OFF_QBUF  = 134873088;          // bf16 L*256        11,010,048
    const size_t OFF_MSOUT = 145883136;          // bf16 L*256
    const size_t OFF_SRCBF = 156893184;          // bf16 L*256
    const size_t OFF_W     = 167903232;
    const size_t W_VW   = OFF_W;                 // 6*256*256 bf16
    const size_t W_OW   = W_VW + 786432;
    const size_t W_AW   = W_OW + 589824;
    const size_t W_PW   = W_AW + 294912;
    const size_t W_F1   = W_PW + 786432;
    const size_t W_F2   = W_F1 + 3145728;
    const size_t W_P5   = W_F2 + 3145728;
    const size_t W_P4   = W_P5 + 1048576;
    const size_t W_P3   = W_P4 + 524288;
    const size_t W_LAT  = W_P3 + 262144;
    const size_t W_OUTW = W_LAT + 131072;
    const size_t W_MASKW= W_OUTW + 1179648;
    const size_t OFF_IMG   = W_MASKW + 1179648;  // bf16 256*65536   33,554,432
    const size_t OFF_STATS = OFF_IMG + 33554432; // 1280 B

    float*  src    = (float*)(wsb + OFF_SRC);
    float*  pos    = (float*)(wsb + OFF_POS);
    float*  value  = (float*)(wsb + OFF_VALUE);
    float*  offs   = (float*)(wsb + OFF_OFFS);
    float*  attw   = (float*)(wsb + OFF_ATTW);
    bf16_t* ffnh   = (bf16_t*)(wsb + OFF_FFNH);
    bf16_t* qbuf   = (bf16_t*)(wsb + OFF_QBUF);
    bf16_t* msout  = (bf16_t*)(wsb + OFF_MSOUT);
    bf16_t* src_bf = (bf16_t*)(wsb + OFF_SRCBF);
    bf16_t* img    = (bf16_t*)(wsb + OFF_IMG);
    float*  stats  = (float*)(wsb + OFF_STATS);

    // projections phase: resXT staged over (dead) ffnh
    bf16_t* res5T = (bf16_t*)(wsb + OFF_FFNH);
    bf16_t* res4T = (bf16_t*)(wsb + OFF_FFNH + 4194304);
    bf16_t* res3T = (bf16_t*)(wsb + OFF_FFNH + 12582912);
    // tail aliases
    float* big0 = (float*)(wsb + OFF_POS);    // 64 MB over pos..attw
    float* big1 = (float*)(wsb + OFF_FFNH);   // 64 MB over ffnh..src_bf
    bf16_t* res2T = (bf16_t*)(wsb + OFF_FFNH);// 32 MB, dead before big1 use

    hipMemsetAsync(stats, 0, 1280, stream);
    dim3 blk(256);

    // ---- weight conversions (transpose f32[K][N] -> bf16[N][K]) ----
    tconv_k<<<dim3(8, 8, 6),  blk, 0, stream>>>(enc_vw, (bf16_t*)(wsb + W_VW), 256, 256,  65536, 65536);
    tconv_k<<<dim3(6, 8, 6),  blk, 0, stream>>>(enc_ow, (bf16_t*)(wsb + W_OW), 256, 192,  49152, 49152);
    tconv_k<<<dim3(3, 8, 6),  blk, 0, stream>>>(enc_aw, (bf16_t*)(wsb + W_AW), 256, 96,   24576, 24576);
    tconv_k<<<dim3(8, 8, 6),  blk, 0, stream>>>(enc_pw, (bf16_t*)(wsb + W_PW), 256, 256,  65536, 65536);
    tconv_k<<<dim3(32, 8, 6), blk, 0, stream>>>(enc_f1w, (bf16_t*)(wsb + W_F1), 256, 1024, 262144, 262144);
    tconv_k<<<dim3(8, 32, 6), blk, 0, stream>>>(enc_f2w, (bf16_t*)(wsb + W_F2), 1024, 256, 262144, 262144);
    tconv_k<<<dim3(8, 64, 1), blk, 0, stream>>>(proj_w5, (bf16_t*)(wsb + W_P5), 2048, 256, 0, 0);
    tconv_k<<<dim3(8, 32, 1), blk, 0, stream>>>(proj_w4, (bf16_t*)(wsb + W_P4), 1024, 256, 0, 0);
    tconv_k<<<dim3(8, 16, 1), blk, 0, stream>>>(proj_w3, (bf16_t*)(wsb + W_P3), 512, 256, 0, 0);
    tconv_k<<<dim3(8, 8, 1),  blk, 0, stream>>>(lat_w,   (bf16_t*)(wsb + W_LAT), 256, 256, 0, 0);
    cvt_k<<<2304, blk, 0, stream>>>(out_w,  (bf16_t*)(wsb + W_OUTW), 589824);
    cvt_k<<<2304, blk, 0, stream>>>(mask_w, (bf16_t*)(wsb + W_MASKW), 589824);
    // image transposes: f32 [C][HW] -> bf16 [HW][C]
    tconv_k<<<dim3(32, 64, 1),  blk, 0, stream>>>(res5, res5T, 2048, 1024, 0, 0);
    tconv_k<<<dim3(128, 32, 1), blk, 0, stream>>>(res4, res4T, 1024, 4096, 0, 0);
    tconv_k<<<dim3(512, 16, 1), blk, 0, stream>>>(res3, res3T, 512, 16384, 0, 0);

    // ---- level projections + GroupNorm ----
    gemm_bf_k<0,false,false,true,false><<<dim3(2, 8), blk, 0, stream>>>(
        res5T, (bf16_t*)(wsb + W_P5), proj_b5, src, nullptr, 1024, 256, 2048);
    gemm_bf_k<0,false,false,true,false><<<dim3(2, 32), blk, 0, stream>>>(
        res4T, (bf16_t*)(wsb + W_P4), proj_b4, src + (size_t)1024 * 256, nullptr, 4096, 256, 1024);
    gemm_bf_k<0,false,false,true,false><<<dim3(2, 128), blk, 0, stream>>>(
        res3T, (bf16_t*)(wsb + W_P3), proj_b3, src + (size_t)5120 * 256, nullptr, 16384, 256, 512);

    gn_stats_k<<<dim3(32, 4), blk, 0, stream>>>(src, 1024, stats + 0);
    gn_stats_k<<<dim3(32, 8), blk, 0, stream>>>(src + (size_t)1024 * 256, 4096, stats + 64);
    gn_stats_k<<<dim3(32, 16), blk, 0, stream>>>(src + (size_t)5120 * 256, 16384, stats + 128);
    gn_apply_k<false><<<1024, blk, 0, stream>>>(src, 1024, stats + 0, gn_g5, gn_b5);
    gn_apply_k<false><<<4096, blk, 0, stream>>>(src + (size_t)1024 * 256, 4096, stats + 64, gn_g4, gn_b4);
    gn_apply_k<false><<<16384, blk, 0, stream>>>(src + (size_t)5120 * 256, 16384, stats + 128, gn_g3, gn_b3);

    cvt_k<<<L, blk, 0, stream>>>(src, src_bf, L * 256);
    pos_embed_k<<<L, blk, 0, stream>>>(pos, level_embed);

    // ---- encoder layers ----
    for (int i = 0; i < 6; ++i) {
        const bf16_t* vwT = (bf16_t*)(wsb + W_VW) + (size_t)i * 65536;
        const bf16_t* owT = (bf16_t*)(wsb + W_OW) + (size_t)i * 49152;
        const bf16_t* awT = (bf16_t*)(wsb + W_AW) + (size_t)i * 24576;
        const bf16_t* pwT = (bf16_t*)(wsb + W_PW) + (size_t)i * 65536;
        const bf16_t* f1T = (bf16_t*)(wsb + W_F1) + (size_t)i * 262144;
        const bf16_t* f2T = (bf16_t*)(wsb + W_F2) + (size_t)i * 262144;
        const float* vb = enc_vb + (size_t)i * 256;
        const float* ob = enc_ob + (size_t)i * 192;
        const float* ab = enc_ab + (size_t)i * 96;
        const float* pb = enc_pb + (size_t)i * 256;
        const float* l1g = enc_ln1g + (size_t)i * 256;
        const float* l1b = enc_ln1b + (size_t)i * 256;
        const float* f1b = enc_f1b + (size_t)i * 1024;
        const float* f2b = enc_f2b + (size_t)i * 256;
        const float* l2g = enc_ln2g + (size_t)i * 256;
        const float* l2b = enc_ln2b + (size_t)i * 256;

        add_k<<<L, blk, 0, stream>>>(src, pos, qbuf, L * 256);
        gemm_bf_k<0,false,false,true,false><<<dim3(2, 168), blk, 0, stream>>>(
            src_bf, vwT, vb, value, nullptr, L, 256, 256);
        gemm_bf_k<0,true,false,true,false><<<dim3(2, 168), blk, 0, stream>>>(
            qbuf, owT, ob, offs, nullptr, L, 192, 256);
        gemm_bf_k<0,true,false,true,false><<<dim3(1, 168), blk, 0, stream>>>(
            qbuf, awT, ab, attw, nullptr, L, 96, 256);
        softmax12_k<<<(L * 8 + 255) / 256, blk, 0, stream>>>(attw, L * 8);
        msdeform_k<<<L, blk, 0, stream>>>(value, offs, attw, msout);
        gemm_bf_k<0,false,false,true,false><<<dim3(2, 168), blk, 0, stream>>>(
            msout, pwT, pb, value, nullptr, L, 256, 256);
        resid_ln_k<<<L, blk, 0, stream>>>(src, value, l1g, l1b, src_bf);
        gemm_bf_k<0,false,true,false,true><<<dim3(8, 168), blk, 0, stream>>>(
            src_bf, f1T, f1b, nullptr, ffnh, L, 1024, 256);
        gemm_bf_k<0,false,false,true,false><<<dim3(2, 168), blk, 0, stream>>>(
            ffnh, f2T, f2b, value, nullptr, L, 256, 1024);
        resid_ln_k<<<L, blk, 0, stream>>>(src, value, l2g, l2b, src_bf);
    }

    // ---- decoder tail ----
    // res2T (over dead ffnh region), lat GEMM -> big0
    tconv_k<<<dim3(2048, 8, 1), blk, 0, stream>>>(res2, res2T, 256, 65536, 0, 0);
    gemm_bf_k<0,false,false,true,false><<<dim3(2, 512), blk, 0, stream>>>(
        res2T, (bf16_t*)(wsb + W_LAT), nullptr, big0, nullptr, 65536, 256, 256);
    gn_stats_k<<<dim3(32, 32), blk, 0, stream>>>(big0, 65536, stats + 192);
    gn_apply_k<false><<<65536, blk, 0, stream>>>(big0, 65536, stats + 192, lat_gn_g, lat_gn_b);
    upsample_add_k<<<65536, blk, 0, stream>>>(big0, src + (size_t)5120 * 256);

    // conv1 (out_w, no bias) via implicit im2col on bf16 CHW image
    tconv_k<<<dim3(8, 2048, 1), blk, 0, stream>>>(big0, img, 65536, 256, 0, 0);
    gemm_bf_k<2,false,false,true,false><<<dim3(2, 512), blk, 0, stream>>>(
        img, (bf16_t*)(wsb + W_OUTW), nullptr, big1, nullptr, 65536, 256, 2304);
    gn_stats_k<<<dim3(32, 32), blk, 0, stream>>>(big1, 65536, stats + 256);
    gn_apply_k<true><<<65536, blk, 0, stream>>>(big1, 65536, stats + 256, out_gn_g, out_gn_b);

    // conv2 (mask_w + bias)
    tconv_k<<<dim3(8, 2048, 1), blk, 0, stream>>>(big1, img, 65536, 256, 0, 0);
    gemm_bf_k<2,false,false,true,false><<<dim3(2, 512), blk, 0, stream>>>(
        img, (bf16_t*)(wsb + W_MASKW), mask_b, big0, nullptr, 65536, 256, 2304);

    transpose_k<<<dim3(2048, 8), blk, 0, stream>>>(big0, (float*)d_out, 65536);
}

// Round 3
// 3778.458 us; speedup vs baseline: 2.6335x; 1.0263x over previous
//
#include <hip/hip_runtime.h>
#include <cstddef>

#define L_TOT 21504

typedef __bf16 bf16_t;
typedef bf16_t bf16x8 __attribute__((ext_vector_type(8)));
typedef float floatx4 __attribute__((ext_vector_type(4)));

__device__ __forceinline__ bf16x8 bf8_zero() {
    bf16x8 v;
#pragma unroll
    for (int i = 0; i < 8; ++i) v[i] = (bf16_t)0.f;
    return v;
}

// ============================ MFMA GEMM ============================
// C[M,N] = A[M,K] (bf16 row-major) x Bt[N,K]^T (bf16, N-major) + bias
// AMODE 0: A row-major bf16
// AMODE 2: implicit im2col of bf16 HWC image (H=W=256, C=256), K order q*256+c
//          (q = kernel tap ky*3+kx of 3x3 SAME). Weights pre-reordered to match.
// Tiles: BM=128, BN=128, BK=32. 256 threads = 4 waves, each wave 64x64 (4x4 frags).
template<int AMODE, bool NBOUND, bool RELU, bool WF32, bool WBF>
__global__ __launch_bounds__(256) void gemm_bf_k(
    const bf16_t* __restrict__ A, const bf16_t* __restrict__ Bt,
    const float* __restrict__ bias, float* __restrict__ C, bf16_t* __restrict__ Cb,
    int M, int N, int K)
{
    __shared__ bf16_t As[128][40];
    __shared__ bf16_t Bs[128][40];
    const int tid = threadIdx.x;
    const int m0 = blockIdx.y * 128, n0 = blockIdx.x * 128;
    const int lane = tid & 63, wv = tid >> 6;
    const int ln16 = lane & 15, quad = lane >> 4;
    const int wm = (wv >> 1) * 64, wn = (wv & 1) * 64;

    floatx4 acc[4][4];
#pragma unroll
    for (int i = 0; i < 4; ++i)
#pragma unroll
        for (int j = 0; j < 4; ++j)
            acc[i][j] = (floatx4){0.f, 0.f, 0.f, 0.f};

    const int srow = tid >> 2;          // 0..63
    const int sseg = (tid & 3) * 8;     // 0,8,16,24

    for (int k0 = 0; k0 < K; k0 += 32) {
        if (AMODE == 0) {
#pragma unroll
            for (int p = 0; p < 2; ++p) {
                int r = srow + p * 64;
                *(bf16x8*)&As[r][sseg] =
                    *(const bf16x8*)&A[(size_t)(m0 + r) * K + k0 + sseg];
            }
        } else {
            int q = k0 >> 8;            // kernel tap
            int c0 = k0 & 255;
            int dy = q / 3 - 1, dx = q % 3 - 1;
#pragma unroll
            for (int p = 0; p < 2; ++p) {
                int r = srow + p * 64;
                int m = m0 + r;
                int yy = (m >> 8) + dy, xx = (m & 255) + dx;
                bf16x8 v;
                if ((unsigned)yy < 256u && (unsigned)xx < 256u)
                    v = *(const bf16x8*)&A[(((size_t)(yy << 8) + xx) << 8) + c0 + sseg];
                else
                    v = bf8_zero();
                *(bf16x8*)&As[r][sseg] = v;
            }
        }
#pragma unroll
        for (int p = 0; p < 2; ++p) {
            int r = srow + p * 64;
            bf16x8 bv;
            if (!NBOUND || (n0 + r) < N)
                bv = *(const bf16x8*)&Bt[(size_t)(n0 + r) * K + k0 + sseg];
            else
                bv = bf8_zero();
            *(bf16x8*)&Bs[r][sseg] = bv;
        }
        __syncthreads();

        bf16x8 af[4], bfv[4];
#pragma unroll
        for (int i = 0; i < 4; ++i)
            af[i] = *(const bf16x8*)&As[wm + i * 16 + ln16][quad * 8];
#pragma unroll
        for (int j = 0; j < 4; ++j)
            bfv[j] = *(const bf16x8*)&Bs[wn + j * 16 + ln16][quad * 8];
#pragma unroll
        for (int i = 0; i < 4; ++i)
#pragma unroll
            for (int j = 0; j < 4; ++j)
                acc[i][j] = __builtin_amdgcn_mfma_f32_16x16x32_bf16(
                    af[i], bfv[j], acc[i][j], 0, 0, 0);
        __syncthreads();
    }

#pragma unroll
    for (int i = 0; i < 4; ++i) {
        int rbase = m0 + wm + i * 16 + quad * 4;
#pragma unroll
        for (int j = 0; j < 4; ++j) {
            int col = n0 + wn + j * 16 + ln16;
            if (NBOUND && col >= N) continue;
            float bv = bias ? bias[col] : 0.f;
#pragma unroll
            for (int r = 0; r < 4; ++r) {
                float v = acc[i][j][r] + bv;
                if (RELU) v = fmaxf(v, 0.f);
                size_t idx = (size_t)(rbase + r) * N + col;
                if (WF32) C[idx] = v;
                if (WBF)  Cb[idx] = (bf16_t)v;
            }
        }
    }
}

// ============================ transpose-convert f32 [R][C] -> bf16 [C][R] ============================
__global__ __launch_bounds__(256) void tconv_k(const float* __restrict__ in,
                                               bf16_t* __restrict__ out,
                                               int R, int Ccols,
                                               size_t in_ls, size_t out_ls)
{
    const float* ip = in + (size_t)blockIdx.z * in_ls;
    bf16_t* op = out + (size_t)blockIdx.z * out_ls;
    __shared__ float t[32][33];
    int r0 = blockIdx.y * 32, c0 = blockIdx.x * 32;
    int x = threadIdx.x & 31, y8 = threadIdx.x >> 5;
#pragma unroll
    for (int i = 0; i < 4; ++i) {
        int r = y8 + i * 8;
        t[r][x] = ip[(size_t)(r0 + r) * Ccols + c0 + x];
    }
    __syncthreads();
#pragma unroll
    for (int i = 0; i < 4; ++i) {
        int r = y8 + i * 8;
        op[(size_t)(c0 + r) * R + r0 + x] = (bf16_t)t[x][r];
    }
}

// ============================ conv weight reorder OIHW -> [o][q*256+c] bf16 ============================
__global__ __launch_bounds__(256) void wreorder_k(const float* __restrict__ w,
                                                  bf16_t* __restrict__ out)
{
    int idx = blockIdx.x * 256 + threadIdx.x;   // 589824 = 256*2304
    if (idx >= 589824) return;
    int o = idx / 2304, rem = idx - o * 2304;
    int q = rem >> 8, c = rem & 255;
    out[idx] = (bf16_t)w[(size_t)o * 2304 + c * 9 + q];
}

// ============================ elementwise f32 -> bf16 ============================
__global__ __launch_bounds__(256) void cvt_k(const float* __restrict__ in,
                                             bf16_t* __restrict__ out, int n)
{
    int i = blockIdx.x * 256 + threadIdx.x;
    if (i < n) out[i] = (bf16_t)in[i];
}

// ============================ add -> bf16 ============================
__global__ __launch_bounds__(256) void add_k(const float* __restrict__ a,
                                             const float* __restrict__ b,
                                             bf16_t* __restrict__ o, int n)
{
    int i = blockIdx.x * 256 + threadIdx.x;
    if (i < n) o[i] = (bf16_t)(a[i] + b[i]);
}

// ============================ GroupNorm ============================
__global__ __launch_bounds__(256) void gn_stats_k(const float* __restrict__ X, int P,
                                                  float* __restrict__ stats)
{
    int g = blockIdx.x;
    size_t total = (size_t)P * 8;
    float a = 0.f, b = 0.f;
    size_t stride = (size_t)gridDim.y * 256;
    for (size_t idx = (size_t)blockIdx.y * 256 + threadIdx.x; idx < total; idx += stride) {
        size_t p = idx >> 3;
        int j = (int)(idx & 7);
        float v = X[p * 256 + g * 8 + j];
        a += v; b += v * v;
    }
#pragma unroll
    for (int o = 32; o > 0; o >>= 1) { a += __shfl_down(a, o, 64); b += __shfl_down(b, o, 64); }
    __shared__ float s1[4], s2[4];
    int lane = threadIdx.x & 63, w = threadIdx.x >> 6;
    if (lane == 0) { s1[w] = a; s2[w] = b; }
    __syncthreads();
    if (threadIdx.x == 0) {
        atomicAdd(&stats[g * 2 + 0], s1[0] + s1[1] + s1[2] + s1[3]);
        atomicAdd(&stats[g * 2 + 1], s2[0] + s2[1] + s2[2] + s2[3]);
    }
}

template<bool RELU>
__global__ __launch_bounds__(256) void gn_apply_k(float* __restrict__ X, int P,
                                                  const float* __restrict__ stats,
                                                  const float* __restrict__ gamma,
                                                  const float* __restrict__ beta)
{
    size_t i = (size_t)blockIdx.x * 256 + threadIdx.x;
    int c = (int)(i & 255), g = c >> 3;
    float cnt = (float)P * 8.f;
    float mean = stats[g * 2] / cnt;
    float var = stats[g * 2 + 1] / cnt - mean * mean;
    float v = (X[i] - mean) * rsqrtf(var + 1e-5f) * gamma[c] + beta[c];
    if (RELU) v = fmaxf(v, 0.f);
    X[i] = v;
}

// ============ fused GN + bilinear-upsample-add + cvt -> bf16 HWC ============
__global__ __launch_bounds__(256) void gn_up_cvt_k(
    const float* __restrict__ X, const float* __restrict__ stats,
    const float* __restrict__ gamma, const float* __restrict__ beta,
    const float* __restrict__ src2, bf16_t* __restrict__ out)
{
    int p = blockIdx.x, d = threadIdx.x;
    int g = d >> 3;
    const float cnt = 65536.f * 8.f;
    float mean = stats[g * 2] / cnt;
    float var = stats[g * 2 + 1] / cnt - mean * mean;
    float v = (X[(size_t)p * 256 + d] - mean) * rsqrtf(var + 1e-5f) * gamma[d] + beta[d];

    int y = p >> 8, x = p & 255;
    float yin = (float)y * 0.5f - 0.25f;
    float xin = (float)x * 0.5f - 0.25f;
    float y0f = floorf(yin), x0f = floorf(xin);
    float fy = yin - y0f, fx = xin - x0f;
    int y0 = (int)y0f, x0 = (int)x0f;
    int y0c = min(max(y0, 0), 127), y1c = min(max(y0 + 1, 0), 127);
    int x0c = min(max(x0, 0), 127), x1c = min(max(x0 + 1, 0), 127);
    float v00 = src2[((size_t)(y0c * 128 + x0c)) * 256 + d];
    float v10 = src2[((size_t)(y0c * 128 + x1c)) * 256 + d];
    float v01 = src2[((size_t)(y1c * 128 + x0c)) * 256 + d];
    float v11 = src2[((size_t)(y1c * 128 + x1c)) * 256 + d];
    float up = v00 * (1.f - fx) * (1.f - fy) + v10 * fx * (1.f - fy)
             + v01 * (1.f - fx) * fy + v11 * fx * fy;
    out[(size_t)p * 256 + d] = (bf16_t)(v + up);
}

// ============ fused GN + ReLU + cvt -> bf16 HWC ============
__global__ __launch_bounds__(256) void gn_relu_cvt_k(
    const float* __restrict__ X, const float* __restrict__ stats,
    const float* __restrict__ gamma, const float* __restrict__ beta,
    bf16_t* __restrict__ out)
{
    size_t i = (size_t)blockIdx.x * 256 + threadIdx.x;
    int c = (int)(i & 255), g = c >> 3;
    const float cnt = 65536.f * 8.f;
    float mean = stats[g * 2] / cnt;
    float var = stats[g * 2 + 1] / cnt - mean * mean;
    float v = (X[i] - mean) * rsqrtf(var + 1e-5f) * gamma[c] + beta[c];
    out[i] = (bf16_t)fmaxf(v, 0.f);
}

// ============================ sine pos embed + level embed ============================
__global__ __launch_bounds__(256) void pos_embed_k(float* __restrict__ pos,
                                                   const float* __restrict__ level_embed)
{
    int l = blockIdx.x, d = threadIdx.x;
    int lvl, Wt, base;
    if (l < 1024)      { lvl = 0; Wt = 32;  base = 0; }
    else if (l < 5120) { lvl = 1; Wt = 64;  base = 1024; }
    else               { lvl = 2; Wt = 128; base = 5120; }
    int pp = l - base;
    int ty = pp / Wt, tx = pp % Wt;
    const float TWO_PI = 6.283185307179586f;
    float e = (d < 128) ? ((float)(ty + 1) * TWO_PI / ((float)Wt + 1e-6f))
                        : ((float)(tx + 1) * TWO_PI / ((float)Wt + 1e-6f));
    int k = d & 127;
    int m = k >> 1;
    float t = powf(10000.f, (float)m * (1.f / 64.f));
    float v = (k & 1) ? cosf(e / t) : sinf(e / t);
    pos[(size_t)l * 256 + d] = v + level_embed[lvl * 256 + d];
}

// ============================ softmax over 12 ============================
__global__ __launch_bounds__(256) void softmax12_k(float* __restrict__ w, int total)
{
    int i = blockIdx.x * 256 + threadIdx.x;
    if (i >= total) return;
    float* p = w + (size_t)i * 12;
    float m = p[0];
#pragma unroll
    for (int j = 1; j < 12; ++j) m = fmaxf(m, p[j]);
    float e[12];
    float s = 0.f;
#pragma unroll
    for (int j = 0; j < 12; ++j) { e[j] = expf(p[j] - m); s += e[j]; }
    float r = 1.f / s;
#pragma unroll
    for (int j = 0; j < 12; ++j) p[j] = e[j] * r;
}

// ============================ deformable sampling (value bf16, out bf16) ============================
__global__ __launch_bounds__(256) void msdeform_k(
    const bf16_t* __restrict__ value, const float* __restrict__ offs,
    const float* __restrict__ attw, bf16_t* __restrict__ out)
{
    int l = blockIdx.x;
    int tid = threadIdx.x;
    int h = tid >> 5, d = tid & 31;
    int Wt, base;
    if (l < 1024)      { Wt = 32;  base = 0; }
    else if (l < 5120) { Wt = 64;  base = 1024; }
    else               { Wt = 128; base = 5120; }
    int pp = l - base;
    int tyy = pp / Wt, txx = pp % Wt;
    float refx = ((float)txx + 0.5f) / (float)Wt;
    float refy = ((float)tyy + 0.5f) / (float)Wt;

    const float* offs_l = offs + (size_t)l * 192 + h * 24;
    const float* attw_l = attw + (size_t)l * 96 + h * 12;
    float acc = 0.f;
#pragma unroll
    for (int lvl = 0; lvl < 3; ++lvl) {
        int Ws = 32 << lvl;
        int start = (lvl == 0) ? 0 : (lvl == 1 ? 1024 : 5120);
        float invW = 1.f / (float)Ws;
#pragma unroll
        for (int p = 0; p < 4; ++p) {
            float ox = offs_l[lvl * 8 + p * 2 + 0];
            float oy = offs_l[lvl * 8 + p * 2 + 1];
            float wgt = attw_l[lvl * 4 + p];
            float gx = (refx + ox * invW) * (float)Ws - 0.5f;
            float gy = (refy + oy * invW) * (float)Ws - 0.5f;
            float x0f = floorf(gx), y0f = floorf(gy);
            float fx = gx - x0f, fy = gy - y0f;
            int x0 = (int)x0f, y0 = (int)y0f;
            float v00 = 0.f, v10 = 0.f, v01 = 0.f, v11 = 0.f;
            if ((unsigned)x0 < (unsigned)Ws && (unsigned)y0 < (unsigned)Ws)
                v00 = (float)value[((size_t)(start + y0 * Ws + x0)) * 256 + h * 32 + d];
            if ((unsigned)(x0 + 1) < (unsigned)Ws && (unsigned)y0 < (unsigned)Ws)
                v10 = (float)value[((size_t)(start + y0 * Ws + x0 + 1)) * 256 + h * 32 + d];
            if ((unsigned)x0 < (unsigned)Ws && (unsigned)(y0 + 1) < (unsigned)Ws)
                v01 = (float)value[((size_t)(start + (y0 + 1) * Ws + x0)) * 256 + h * 32 + d];
            if ((unsigned)(x0 + 1) < (unsigned)Ws && (unsigned)(y0 + 1) < (unsigned)Ws)
                v11 = (float)value[((size_t)(start + (y0 + 1) * Ws + x0 + 1)) * 256 + h * 32 + d];
            float s = v00 * (1.f - fx) * (1.f - fy) + v10 * fx * (1.f - fy)
                    + v01 * (1.f - fx) * fy + v11 * fx * fy;
            acc += wgt * s;
        }
    }
    out[(size_t)l * 256 + tid] = (bf16_t)acc;
}

// ============================ residual + LayerNorm (dual f32 + bf16 out) ============================
__global__ __launch_bounds__(256) void resid_ln_k(
    float* __restrict__ src, const float* __restrict__ r,
    const float* __restrict__ g, const float* __restrict__ b,
    bf16_t* __restrict__ src_bf)
{
    int l = blockIdx.x, tid = threadIdx.x;
    float v = src[(size_t)l * 256 + tid] + r[(size_t)l * 256 + tid];
    float a = v, s2 = v * v;
#pragma unroll
    for (int o = 32; o > 0; o >>= 1) { a += __shfl_down(a, o, 64); s2 += __shfl_down(s2, o, 64); }
    __shared__ float sh1[4], sh2[4], res[2];
    int lane = tid & 63, w = tid >> 6;
    if (lane == 0) { sh1[w] = a; sh2[w] = s2; }
    __syncthreads();
    if (tid == 0) {
        float A = sh1[0] + sh1[1] + sh1[2] + sh1[3];
        float B = sh2[0] + sh2[1] + sh2[2] + sh2[3];
        float mu = A * (1.f / 256.f);
        res[0] = mu;
        res[1] = rsqrtf(B * (1.f / 256.f) - mu * mu + 1e-5f);
    }
    __syncthreads();
    float o = (v - res[0]) * res[1] * g[tid] + b[tid];
    src[(size_t)l * 256 + tid] = o;
    src_bf[(size_t)l * 256 + tid] = (bf16_t)o;
}

// ============================ transpose f32 (P,256) -> (256,P) ============================
__global__ __launch_bounds__(256) void transpose_k(const float* __restrict__ in,
                                                   float* __restrict__ out, int P)
{
    __shared__ float t[32][33];
    int p0 = blockIdx.x * 32, c0 = blockIdx.y * 32;
    int x = threadIdx.x & 31, y = threadIdx.x >> 5;
#pragma unroll
    for (int i = 0; i < 4; ++i) {
        int r = y + i * 8;
        t[r][x] = in[(size_t)(p0 + r) * 256 + c0 + x];
    }
    __syncthreads();
#pragma unroll
    for (int i = 0; i < 4; ++i) {
        int r = y + i * 8;
        out[(size_t)(c0 + r) * P + p0 + x] = t[x][r];
    }
}

// ============================ host launcher ============================
extern "C" void kernel_launch(void* const* d_in, const int* in_sizes, int n_in,
                              void* d_out, int out_size, void* d_ws, size_t ws_size,
                              hipStream_t stream) {
    const float* res2    = (const float*)d_in[0];
    const float* res3    = (const float*)d_in[1];
    const float* res4    = (const float*)d_in[2];
    const float* res5    = (const float*)d_in[3];
    const float* proj_w5 = (const float*)d_in[4];
    const float* proj_b5 = (const float*)d_in[5];
    const float* gn_g5   = (const float*)d_in[6];
    const float* gn_b5   = (const float*)d_in[7];
    const float* proj_w4 = (const float*)d_in[8];
    const float* proj_b4 = (const float*)d_in[9];
    const float* gn_g4   = (const float*)d_in[10];
    const float* gn_b4   = (const float*)d_in[11];
    const float* proj_w3 = (const float*)d_in[12];
    const float* proj_b3 = (const float*)d_in[13];
    const float* gn_g3   = (const float*)d_in[14];
    const float* gn_b3   = (const float*)d_in[15];
    const float* level_embed = (const float*)d_in[16];
    const float* enc_vw  = (const float*)d_in[17];
    const float* enc_vb  = (const float*)d_in[18];
    const float* enc_ow  = (const float*)d_in[19];
    const float* enc_ob  = (const float*)d_in[20];
    const float* enc_aw  = (const float*)d_in[21];
    const float* enc_ab  = (const float*)d_in[22];
    const float* enc_pw  = (const float*)d_in[23];
    const float* enc_pb  = (const float*)d_in[24];
    const float* enc_ln1g = (const float*)d_in[25];
    const float* enc_ln1b = (const float*)d_in[26];
    const float* enc_f1w = (const float*)d_in[27];
    const float* enc_f1b = (const float*)d_in[28];
    const float* enc_f2w = (const float*)d_in[29];
    const float* enc_f2b = (const float*)d_in[30];
    const float* enc_ln2g = (const float*)d_in[31];
    const float* enc_ln2b = (const float*)d_in[32];
    const float* lat_w   = (const float*)d_in[33];
    const float* lat_gn_g = (const float*)d_in[34];
    const float* lat_gn_b = (const float*)d_in[35];
    const float* out_w   = (const float*)d_in[36];
    const float* out_gn_g = (const float*)d_in[37];
    const float* out_gn_b = (const float*)d_in[38];
    const float* mask_w  = (const float*)d_in[39];
    const float* mask_b  = (const float*)d_in[40];

    char* wsb = (char*)d_ws;
    const int L = L_TOT;

    // ---- workspace layout (bytes) ----
    const size_t OFF_SRC   = 0;                  // f32 L*256
    const size_t OFF_POS   = 22020096;           // f32 L*256
    const size_t OFF_TMPF  = 44040192;           // f32 L*256 (gemm f32 outs)
    const size_t OFF_OFFS  = 66060288;           // f32 L*192
    const size_t OFF_ATTW  = 82575360;           // f32 L*96
    const size_t OFF_FFNH  = 90832896;           // bf16 L*1024 (also valbf alias)
    const size_t OFF_QBUF  = 134873088;          // bf16 L*256
    const size_t OFF_MSOUT = 145883136;          // bf16 L*256
    const size_t OFF_SRCBF = 156893184;          // bf16 L*256
    const size_t OFF_W     = 167903232;
    const size_t W_VW   = OFF_W;                 // 6*256*256 bf16
    const size_t W_OW   = W_VW + 786432;
    const size_t W_AW   = W_OW + 589824;
    const size_t W_PW   = W_AW + 294912;
    const size_t W_F1   = W_PW + 786432;
    const size_t W_F2   = W_F1 + 3145728;
    const size_t W_P5   = W_F2 + 3145728;
    const size_t W_P4   = W_P5 + 1048576;
    const size_t W_P3   = W_P4 + 524288;
    const size_t W_LAT  = W_P3 + 262144;
    const size_t W_OUTW = W_LAT + 131072;
    const size_t W_MASKW= W_OUTW + 1179648;
    const size_t OFF_IMG   = W_MASKW + 1179648;  // bf16 65536*256 (HWC)
    const size_t OFF_STATS = OFF_IMG + 33554432;

    float*  src    = (float*)(wsb + OFF_SRC);
    float*  pos    = (float*)(wsb + OFF_POS);
    float*  tmpf   = (float*)(wsb + OFF_TMPF);
    float*  offs   = (float*)(wsb + OFF_OFFS);
    float*  attw   = (float*)(wsb + OFF_ATTW);
    bf16_t* ffnh   = (bf16_t*)(wsb + OFF_FFNH);
    bf16_t* valbf  = (bf16_t*)(wsb + OFF_FFNH);   // alias: disjoint live ranges
    bf16_t* qbuf   = (bf16_t*)(wsb + OFF_QBUF);
    bf16_t* msout  = (bf16_t*)(wsb + OFF_MSOUT);
    bf16_t* src_bf = (bf16_t*)(wsb + OFF_SRCBF);
    bf16_t* img    = (bf16_t*)(wsb + OFF_IMG);
    float*  stats  = (float*)(wsb + OFF_STATS);

    // projections phase: resXT staged over (dead) ffnh
    bf16_t* res5T = (bf16_t*)(wsb + OFF_FFNH);
    bf16_t* res4T = (bf16_t*)(wsb + OFF_FFNH + 4194304);
    bf16_t* res3T = (bf16_t*)(wsb + OFF_FFNH + 12582912);
    // tail aliases
    float* big0 = (float*)(wsb + OFF_POS);    // 64 MB over pos..attw
    float* big1 = (float*)(wsb + OFF_FFNH);   // 64 MB over ffnh..src_bf
    bf16_t* res2T = (bf16_t*)(wsb + OFF_FFNH);// 32 MB, dead before big1 use

    hipMemsetAsync(stats, 0, 1280, stream);
    dim3 blk(256);

    // ---- weight conversions ----
    tconv_k<<<dim3(8, 8, 6),  blk, 0, stream>>>(enc_vw, (bf16_t*)(wsb + W_VW), 256, 256,  65536, 65536);
    tconv_k<<<dim3(6, 8, 6),  blk, 0, stream>>>(enc_ow, (bf16_t*)(wsb + W_OW), 256, 192,  49152, 49152);
    tconv_k<<<dim3(3, 8, 6),  blk, 0, stream>>>(enc_aw, (bf16_t*)(wsb + W_AW), 256, 96,   24576, 24576);
    tconv_k<<<dim3(8, 8, 6),  blk, 0, stream>>>(enc_pw, (bf16_t*)(wsb + W_PW), 256, 256,  65536, 65536);
    tconv_k<<<dim3(32, 8, 6), blk, 0, stream>>>(enc_f1w, (bf16_t*)(wsb + W_F1), 256, 1024, 262144, 262144);
    tconv_k<<<dim3(8, 32, 6), blk, 0, stream>>>(enc_f2w, (bf16_t*)(wsb + W_F2), 1024, 256, 262144, 262144);
    tconv_k<<<dim3(8, 64, 1), blk, 0, stream>>>(proj_w5, (bf16_t*)(wsb + W_P5), 2048, 256, 0, 0);
    tconv_k<<<dim3(8, 32, 1), blk, 0, stream>>>(proj_w4, (bf16_t*)(wsb + W_P4), 1024, 256, 0, 0);
    tconv_k<<<dim3(8, 16, 1), blk, 0, stream>>>(proj_w3, (bf16_t*)(wsb + W_P3), 512, 256, 0, 0);
    tconv_k<<<dim3(8, 8, 1),  blk, 0, stream>>>(lat_w,   (bf16_t*)(wsb + W_LAT), 256, 256, 0, 0);
    wreorder_k<<<2304, blk, 0, stream>>>(out_w,  (bf16_t*)(wsb + W_OUTW));
    wreorder_k<<<2304, blk, 0, stream>>>(mask_w, (bf16_t*)(wsb + W_MASKW));
    // image transposes: f32 [C][HW] -> bf16 [HW][C]
    tconv_k<<<dim3(32, 64, 1),  blk, 0, stream>>>(res5, res5T, 2048, 1024, 0, 0);
    tconv_k<<<dim3(128, 32, 1), blk, 0, stream>>>(res4, res4T, 1024, 4096, 0, 0);
    tconv_k<<<dim3(512, 16, 1), blk, 0, stream>>>(res3, res3T, 512, 16384, 0, 0);

    // ---- level projections + GroupNorm ----
    gemm_bf_k<0,false,false,true,false><<<dim3(2, 8), blk, 0, stream>>>(
        res5T, (bf16_t*)(wsb + W_P5), proj_b5, src, nullptr, 1024, 256, 2048);
    gemm_bf_k<0,false,false,true,false><<<dim3(2, 32), blk, 0, stream>>>(
        res4T, (bf16_t*)(wsb + W_P4), proj_b4, src + (size_t)1024 * 256, nullptr, 4096, 256, 1024);
    gemm_bf_k<0,false,false,true,false><<<dim3(2, 128), blk, 0, stream>>>(
        res3T, (bf16_t*)(wsb + W_P3), proj_b3, src + (size_t)5120 * 256, nullptr, 16384, 256, 512);

    gn_stats_k<<<dim3(32, 4), blk, 0, stream>>>(src, 1024, stats + 0);
    gn_stats_k<<<dim3(32, 8), blk, 0, stream>>>(src + (size_t)1024 * 256, 4096, stats + 64);
    gn_stats_k<<<dim3(32, 16), blk, 0, stream>>>(src + (size_t)5120 * 256, 16384, stats + 128);
    gn_apply_k<false><<<1024, blk, 0, stream>>>(src, 1024, stats + 0, gn_g5, gn_b5);
    gn_apply_k<false><<<4096, blk, 0, stream>>>(src + (size_t)1024 * 256, 4096, stats + 64, gn_g4, gn_b4);
    gn_apply_k<false><<<16384, blk, 0, stream>>>(src + (size_t)5120 * 256, 16384, stats + 128, gn_g3, gn_b3);

    cvt_k<<<L, blk, 0, stream>>>(src, src_bf, L * 256);
    pos_embed_k<<<L, blk, 0, stream>>>(pos, level_embed);

    // ---- encoder layers ----
    for (int i = 0; i < 6; ++i) {
        const bf16_t* vwT = (bf16_t*)(wsb + W_VW) + (size_t)i * 65536;
        const bf16_t* owT = (bf16_t*)(wsb + W_OW) + (size_t)i * 49152;
        const bf16_t* awT = (bf16_t*)(wsb + W_AW) + (size_t)i * 24576;
        const bf16_t* pwT = (bf16_t*)(wsb + W_PW) + (size_t)i * 65536;
        const bf16_t* f1T = (bf16_t*)(wsb + W_F1) + (size_t)i * 262144;
        const bf16_t* f2T = (bf16_t*)(wsb + W_F2) + (size_t)i * 262144;
        const float* vb = enc_vb + (size_t)i * 256;
        const float* ob = enc_ob + (size_t)i * 192;
        const float* ab = enc_ab + (size_t)i * 96;
        const float* pb = enc_pb + (size_t)i * 256;
        const float* l1g = enc_ln1g + (size_t)i * 256;
        const float* l1b = enc_ln1b + (size_t)i * 256;
        const float* f1b = enc_f1b + (size_t)i * 1024;
        const float* f2b = enc_f2b + (size_t)i * 256;
        const float* l2g = enc_ln2g + (size_t)i * 256;
        const float* l2b = enc_ln2b + (size_t)i * 256;

        add_k<<<L, blk, 0, stream>>>(src, pos, qbuf, L * 256);
        gemm_bf_k<0,false,false,false,true><<<dim3(2, 168), blk, 0, stream>>>(
            src_bf, vwT, vb, nullptr, valbf, L, 256, 256);
        gemm_bf_k<0,true,false,true,false><<<dim3(2, 168), blk, 0, stream>>>(
            qbuf, owT, ob, offs, nullptr, L, 192, 256);
        gemm_bf_k<0,true,false,true,false><<<dim3(1, 168), blk, 0, stream>>>(
            qbuf, awT, ab, attw, nullptr, L, 96, 256);
        softmax12_k<<<(L * 8 + 255) / 256, blk, 0, stream>>>(attw, L * 8);
        msdeform_k<<<L, blk, 0, stream>>>(valbf, offs, attw, msout);
        gemm_bf_k<0,false,false,true,false><<<dim3(2, 168), blk, 0, stream>>>(
            msout, pwT, pb, tmpf, nullptr, L, 256, 256);
        resid_ln_k<<<L, blk, 0, stream>>>(src, tmpf, l1g, l1b, src_bf);
        gemm_bf_k<0,false,true,false,true><<<dim3(8, 168), blk, 0, stream>>>(
            src_bf, f1T, f1b, nullptr, ffnh, L, 1024, 256);
        gemm_bf_k<0,false,false,true,false><<<dim3(2, 168), blk, 0, stream>>>(
            ffnh, f2T, f2b, tmpf, nullptr, L, 256, 1024);
        resid_ln_k<<<L, blk, 0, stream>>>(src, tmpf, l2g, l2b, src_bf);
    }

    // ---- decoder tail ----
    tconv_k<<<dim3(2048, 8, 1), blk, 0, stream>>>(res2, res2T, 256, 65536, 0, 0);
    gemm_bf_k<0,false,false,true,false><<<dim3(2, 512), blk, 0, stream>>>(
        res2T, (bf16_t*)(wsb + W_LAT), nullptr, big0, nullptr, 65536, 256, 256);
    gn_stats_k<<<dim3(32, 32), blk, 0, stream>>>(big0, 65536, stats + 192);
    // fused GN + upsample-add + cvt -> img (bf16 HWC)
    gn_up_cvt_k<<<65536, blk, 0, stream>>>(big0, stats + 192, lat_gn_g, lat_gn_b,
                                           src + (size_t)5120 * 256, img);

    // conv1 (out_w, no bias): implicit im2col on bf16 HWC image
    gemm_bf_k<2,false,false,true,false><<<dim3(2, 512), blk, 0, stream>>>(
        img, (bf16_t*)(wsb + W_OUTW), nullptr, big1, nullptr, 65536, 256, 2304);
    gn_stats_k<<<dim3(32, 32), blk, 0, stream>>>(big1, 65536, stats + 256);
    gn_relu_cvt_k<<<65536, blk, 0, stream>>>(big1, stats + 256, out_gn_g, out_gn_b, img);

    // conv2 (mask_w + bias)
    gemm_bf_k<2,false,false,true,false><<<dim3(2, 512), blk, 0, stream>>>(
        img, (bf16_t*)(wsb + W_MASKW), mask_b, big0, nullptr, 65536, 256, 2304);

    transpose_k<<<dim3(2048, 8), blk, 0, stream>>>(big0, (float*)d_out, 65536);
}

// Round 4
// 2325.148 us; speedup vs baseline: 4.2795x; 1.6250x over previous
//
#include <hip/hip_runtime.h>
#include <cstddef>

#define L_TOT 21504

typedef __bf16 bf16_t;
typedef bf16_t bf16x8 __attribute__((ext_vector_type(8)));
typedef bf16_t bf16x4 __attribute__((ext_vector_type(4)));
typedef float floatx4 __attribute__((ext_vector_type(4)));

__device__ __forceinline__ bf16x8 bf8_zero() {
    bf16x8 v;
#pragma unroll
    for (int i = 0; i < 8; ++i) v[i] = (bf16_t)0.f;
    return v;
}

// ============================ MFMA GEMM ============================
// C[M,N] = A[M,K] (bf16 row-major) x Bt[N,K]^T (bf16, N-major) + bias
// AMODE 0: A row-major bf16
// AMODE 2: implicit im2col of bf16 HWC image (H=W=256, C=256), K order q*256+c
// Tiles: BM=128, BN=128, BK=32. 256 threads = 4 waves, each wave 64x64 (4x4 frags).
template<int AMODE, bool NBOUND, bool RELU, bool WF32, bool WBF>
__global__ __launch_bounds__(256) void gemm_bf_k(
    const bf16_t* __restrict__ A, const bf16_t* __restrict__ Bt,
    const float* __restrict__ bias, float* __restrict__ C, bf16_t* __restrict__ Cb,
    int M, int N, int K)
{
    __shared__ bf16_t As[128][40];
    __shared__ bf16_t Bs[128][40];
    const int tid = threadIdx.x;
    const int m0 = blockIdx.y * 128, n0 = blockIdx.x * 128;
    const int lane = tid & 63, wv = tid >> 6;
    const int ln16 = lane & 15, quad = lane >> 4;
    const int wm = (wv >> 1) * 64, wn = (wv & 1) * 64;

    floatx4 acc[4][4];
#pragma unroll
    for (int i = 0; i < 4; ++i)
#pragma unroll
        for (int j = 0; j < 4; ++j)
            acc[i][j] = (floatx4){0.f, 0.f, 0.f, 0.f};

    const int srow = tid >> 2;          // 0..63
    const int sseg = (tid & 3) * 8;     // 0,8,16,24

    for (int k0 = 0; k0 < K; k0 += 32) {
        if (AMODE == 0) {
#pragma unroll
            for (int p = 0; p < 2; ++p) {
                int r = srow + p * 64;
                *(bf16x8*)&As[r][sseg] =
                    *(const bf16x8*)&A[(size_t)(m0 + r) * K + k0 + sseg];
            }
        } else {
            int q = k0 >> 8;            // kernel tap
            int c0 = k0 & 255;
            int dy = q / 3 - 1, dx = q % 3 - 1;
#pragma unroll
            for (int p = 0; p < 2; ++p) {
                int r = srow + p * 64;
                int m = m0 + r;
                int yy = (m >> 8) + dy, xx = (m & 255) + dx;
                bf16x8 v;
                if ((unsigned)yy < 256u && (unsigned)xx < 256u)
                    v = *(const bf16x8*)&A[(((size_t)(yy << 8) + xx) << 8) + c0 + sseg];
                else
                    v = bf8_zero();
                *(bf16x8*)&As[r][sseg] = v;
            }
        }
#pragma unroll
        for (int p = 0; p < 2; ++p) {
            int r = srow + p * 64;
            bf16x8 bv;
            if (!NBOUND || (n0 + r) < N)
                bv = *(const bf16x8*)&Bt[(size_t)(n0 + r) * K + k0 + sseg];
            else
                bv = bf8_zero();
            *(bf16x8*)&Bs[r][sseg] = bv;
        }
        __syncthreads();

        bf16x8 af[4], bfv[4];
#pragma unroll
        for (int i = 0; i < 4; ++i)
            af[i] = *(const bf16x8*)&As[wm + i * 16 + ln16][quad * 8];
#pragma unroll
        for (int j = 0; j < 4; ++j)
            bfv[j] = *(const bf16x8*)&Bs[wn + j * 16 + ln16][quad * 8];
#pragma unroll
        for (int i = 0; i < 4; ++i)
#pragma unroll
            for (int j = 0; j < 4; ++j)
                acc[i][j] = __builtin_amdgcn_mfma_f32_16x16x32_bf16(
                    af[i], bfv[j], acc[i][j], 0, 0, 0);
        __syncthreads();
    }

#pragma unroll
    for (int i = 0; i < 4; ++i) {
        int rbase = m0 + wm + i * 16 + quad * 4;
#pragma unroll
        for (int j = 0; j < 4; ++j) {
            int col = n0 + wn + j * 16 + ln16;
            if (NBOUND && col >= N) continue;
            float bv = bias ? bias[col] : 0.f;
#pragma unroll
            for (int r = 0; r < 4; ++r) {
                float v = acc[i][j][r] + bv;
                if (RELU) v = fmaxf(v, 0.f);
                size_t idx = (size_t)(rbase + r) * N + col;
                if (WF32) C[idx] = v;
                if (WBF)  Cb[idx] = (bf16_t)v;
            }
        }
    }
}

// ============================ transpose-convert f32 [R][C] -> bf16 [C][R] ============================
__global__ __launch_bounds__(256) void tconv_k(const float* __restrict__ in,
                                               bf16_t* __restrict__ out,
                                               int R, int Ccols,
                                               size_t in_ls, size_t out_ls)
{
    const float* ip = in + (size_t)blockIdx.z * in_ls;
    bf16_t* op = out + (size_t)blockIdx.z * out_ls;
    __shared__ float t[32][33];
    int r0 = blockIdx.y * 32, c0 = blockIdx.x * 32;
    int x = threadIdx.x & 31, y8 = threadIdx.x >> 5;
#pragma unroll
    for (int i = 0; i < 4; ++i) {
        int r = y8 + i * 8;
        t[r][x] = ip[(size_t)(r0 + r) * Ccols + c0 + x];
    }
    __syncthreads();
#pragma unroll
    for (int i = 0; i < 4; ++i) {
        int r = y8 + i * 8;
        op[(size_t)(c0 + r) * R + r0 + x] = (bf16_t)t[x][r];
    }
}

// ============================ conv weight reorder OIHW -> [o][q*256+c] bf16 ============================
__global__ __launch_bounds__(256) void wreorder_k(const float* __restrict__ w,
                                                  bf16_t* __restrict__ out)
{
    int idx = blockIdx.x * 256 + threadIdx.x;   // 589824 = 256*2304
    if (idx >= 589824) return;
    int o = idx / 2304, rem = idx - o * 2304;
    int q = rem >> 8, c = rem & 255;
    out[idx] = (bf16_t)w[(size_t)o * 2304 + c * 9 + q];
}

// ============================ elementwise f32 -> bf16 ============================
__global__ __launch_bounds__(256) void cvt_k(const float* __restrict__ in,
                                             bf16_t* __restrict__ out, int n)
{
    int i = blockIdx.x * 256 + threadIdx.x;
    if (i < n) out[i] = (bf16_t)in[i];
}

// ============================ add -> bf16 ============================
__global__ __launch_bounds__(256) void add_k(const float* __restrict__ a,
                                             const float* __restrict__ b,
                                             bf16_t* __restrict__ o, int n)
{
    int i = blockIdx.x * 256 + threadIdx.x;
    if (i < n) o[i] = (bf16_t)(a[i] + b[i]);
}

// ============================ GroupNorm ============================
__global__ __launch_bounds__(256) void gn_stats_k(const float* __restrict__ X, int P,
                                                  float* __restrict__ stats)
{
    int g = blockIdx.x;
    size_t total = (size_t)P * 8;
    float a = 0.f, b = 0.f;
    size_t stride = (size_t)gridDim.y * 256;
    for (size_t idx = (size_t)blockIdx.y * 256 + threadIdx.x; idx < total; idx += stride) {
        size_t p = idx >> 3;
        int j = (int)(idx & 7);
        float v = X[p * 256 + g * 8 + j];
        a += v; b += v * v;
    }
#pragma unroll
    for (int o = 32; o > 0; o >>= 1) { a += __shfl_down(a, o, 64); b += __shfl_down(b, o, 64); }
    __shared__ float s1[4], s2[4];
    int lane = threadIdx.x & 63, w = threadIdx.x >> 6;
    if (lane == 0) { s1[w] = a; s2[w] = b; }
    __syncthreads();
    if (threadIdx.x == 0) {
        atomicAdd(&stats[g * 2 + 0], s1[0] + s1[1] + s1[2] + s1[3]);
        atomicAdd(&stats[g * 2 + 1], s2[0] + s2[1] + s2[2] + s2[3]);
    }
}

template<bool RELU>
__global__ __launch_bounds__(256) void gn_apply_k(float* __restrict__ X, int P,
                                                  const float* __restrict__ stats,
                                                  const float* __restrict__ gamma,
                                                  const float* __restrict__ beta)
{
    size_t i = (size_t)blockIdx.x * 256 + threadIdx.x;
    int c = (int)(i & 255), g = c >> 3;
    float cnt = (float)P * 8.f;
    float mean = stats[g * 2] / cnt;
    float var = stats[g * 2 + 1] / cnt - mean * mean;
    float v = (X[i] - mean) * rsqrtf(var + 1e-5f) * gamma[c] + beta[c];
    if (RELU) v = fmaxf(v, 0.f);
    X[i] = v;
}

// ============ fused GN + bilinear-upsample-add + cvt -> bf16 HWC ============
__global__ __launch_bounds__(256) void gn_up_cvt_k(
    const float* __restrict__ X, const float* __restrict__ stats,
    const float* __restrict__ gamma, const float* __restrict__ beta,
    const float* __restrict__ src2, bf16_t* __restrict__ out)
{
    int p = blockIdx.x, d = threadIdx.x;
    int g = d >> 3;
    const float cnt = 65536.f * 8.f;
    float mean = stats[g * 2] / cnt;
    float var = stats[g * 2 + 1] / cnt - mean * mean;
    float v = (X[(size_t)p * 256 + d] - mean) * rsqrtf(var + 1e-5f) * gamma[d] + beta[d];

    int y = p >> 8, x = p & 255;
    float yin = (float)y * 0.5f - 0.25f;
    float xin = (float)x * 0.5f - 0.25f;
    float y0f = floorf(yin), x0f = floorf(xin);
    float fy = yin - y0f, fx = xin - x0f;
    int y0 = (int)y0f, x0 = (int)x0f;
    int y0c = min(max(y0, 0), 127), y1c = min(max(y0 + 1, 0), 127);
    int x0c = min(max(x0, 0), 127), x1c = min(max(x0 + 1, 0), 127);
    float v00 = src2[((size_t)(y0c * 128 + x0c)) * 256 + d];
    float v10 = src2[((size_t)(y0c * 128 + x1c)) * 256 + d];
    float v01 = src2[((size_t)(y1c * 128 + x0c)) * 256 + d];
    float v11 = src2[((size_t)(y1c * 128 + x1c)) * 256 + d];
    float up = v00 * (1.f - fx) * (1.f - fy) + v10 * fx * (1.f - fy)
             + v01 * (1.f - fx) * fy + v11 * fx * fy;
    out[(size_t)p * 256 + d] = (bf16_t)(v + up);
}

// ============ fused GN + ReLU + cvt -> bf16 HWC ============
__global__ __launch_bounds__(256) void gn_relu_cvt_k(
    const float* __restrict__ X, const float* __restrict__ stats,
    const float* __restrict__ gamma, const float* __restrict__ beta,
    bf16_t* __restrict__ out)
{
    size_t i = (size_t)blockIdx.x * 256 + threadIdx.x;
    int c = (int)(i & 255), g = c >> 3;
    const float cnt = 65536.f * 8.f;
    float mean = stats[g * 2] / cnt;
    float var = stats[g * 2 + 1] / cnt - mean * mean;
    float v = (X[i] - mean) * rsqrtf(var + 1e-5f) * gamma[c] + beta[c];
    out[i] = (bf16_t)fmaxf(v, 0.f);
}

// ============================ sine pos embed + level embed ============================
__global__ __launch_bounds__(256) void pos_embed_k(float* __restrict__ pos,
                                                   const float* __restrict__ level_embed)
{
    int l = blockIdx.x, d = threadIdx.x;
    int lvl, Wt, base;
    if (l < 1024)      { lvl = 0; Wt = 32;  base = 0; }
    else if (l < 5120) { lvl = 1; Wt = 64;  base = 1024; }
    else               { lvl = 2; Wt = 128; base = 5120; }
    int pp = l - base;
    int ty = pp / Wt, tx = pp % Wt;
    const float TWO_PI = 6.283185307179586f;
    float e = (d < 128) ? ((float)(ty + 1) * TWO_PI / ((float)Wt + 1e-6f))
                        : ((float)(tx + 1) * TWO_PI / ((float)Wt + 1e-6f));
    int k = d & 127;
    int m = k >> 1;
    float t = powf(10000.f, (float)m * (1.f / 64.f));
    float v = (k & 1) ? cosf(e / t) : sinf(e / t);
    pos[(size_t)l * 256 + d] = v + level_embed[lvl * 256 + d];
}

// ============================ softmax over 12 ============================
__global__ __launch_bounds__(256) void softmax12_k(float* __restrict__ w, int total)
{
    int i = blockIdx.x * 256 + threadIdx.x;
    if (i >= total) return;
    float* p = w + (size_t)i * 12;
    float m = p[0];
#pragma unroll
    for (int j = 1; j < 12; ++j) m = fmaxf(m, p[j]);
    float e[12];
    float s = 0.f;
#pragma unroll
    for (int j = 0; j < 12; ++j) { e[j] = expf(p[j] - m); s += e[j]; }
    float r = 1.f / s;
#pragma unroll
    for (int j = 0; j < 12; ++j) p[j] = e[j] * r;
}

// ============================ deformable sampling ============================
// 1 wave = 1 token; lane = h*8 + d4 (each lane covers 4 channels via 8B loads).
// block = 256 threads = 4 tokens.
__global__ __launch_bounds__(256) void msdeform_k(
    const bf16_t* __restrict__ value, const float* __restrict__ offs,
    const float* __restrict__ attw, bf16_t* __restrict__ out)
{
    int t = blockIdx.x * 4 + (threadIdx.x >> 6);
    int lane = threadIdx.x & 63;
    int h = lane >> 3, d4 = (lane & 7) << 2;
    int ch = h * 32 + d4;

    int Wt, base, sh;
    if (t < 1024)      { Wt = 32;  base = 0;    sh = 5; }
    else if (t < 5120) { Wt = 64;  base = 1024; sh = 6; }
    else               { Wt = 128; base = 5120; sh = 7; }
    int pp = t - base;
    int tyy = pp >> sh, txx = pp & (Wt - 1);
    float refx = ((float)txx + 0.5f) / (float)Wt;
    float refy = ((float)tyy + 0.5f) / (float)Wt;

    const float* offs_l = offs + (size_t)t * 192 + h * 24;
    const float* attw_l = attw + (size_t)t * 96 + h * 12;

    float a0 = 0.f, a1 = 0.f, a2 = 0.f, a3 = 0.f;
#pragma unroll
    for (int lvl = 0; lvl < 3; ++lvl) {
        int Ws = 32 << lvl;
        int start = (lvl == 0) ? 0 : (lvl == 1 ? 1024 : 5120);
        float invW = 1.f / (float)Ws;
#pragma unroll
        for (int p = 0; p < 4; ++p) {
            float ox = offs_l[lvl * 8 + p * 2 + 0];
            float oy = offs_l[lvl * 8 + p * 2 + 1];
            float wgt = attw_l[lvl * 4 + p];
            float gx = (refx + ox * invW) * (float)Ws - 0.5f;
            float gy = (refy + oy * invW) * (float)Ws - 0.5f;
            float x0f = floorf(gx), y0f = floorf(gy);
            float fx = gx - x0f, fy = gy - y0f;
            int x0 = (int)x0f, y0 = (int)y0f;
            float w00 = wgt * (1.f - fx) * (1.f - fy);
            float w10 = wgt * fx * (1.f - fy);
            float w01 = wgt * (1.f - fx) * fy;
            float w11 = wgt * fx * fy;
            bool vx0 = (unsigned)x0 < (unsigned)Ws;
            bool vx1 = (unsigned)(x0 + 1) < (unsigned)Ws;
            bool vy0 = (unsigned)y0 < (unsigned)Ws;
            bool vy1 = (unsigned)(y0 + 1) < (unsigned)Ws;
            size_t row0 = ((size_t)(start + y0 * Ws + x0)) * 256 + ch;
            size_t row1 = row0 + (size_t)Ws * 256;
            if (vx0 && vy0) {
                bf16x4 v = *(const bf16x4*)&value[row0];
                a0 += w00 * (float)v[0]; a1 += w00 * (float)v[1];
                a2 += w00 * (float)v[2]; a3 += w00 * (float)v[3];
            }
            if (vx1 && vy0) {
                bf16x4 v = *(const bf16x4*)&value[row0 + 256];
                a0 += w10 * (float)v[0]; a1 += w10 * (float)v[1];
                a2 += w10 * (float)v[2]; a3 += w10 * (float)v[3];
            }
            if (vx0 && vy1) {
                bf16x4 v = *(const bf16x4*)&value[row1];
                a0 += w01 * (float)v[0]; a1 += w01 * (float)v[1];
                a2 += w01 * (float)v[2]; a3 += w01 * (float)v[3];
            }
            if (vx1 && vy1) {
                bf16x4 v = *(const bf16x4*)&value[row1 + 256];
                a0 += w11 * (float)v[0]; a1 += w11 * (float)v[1];
                a2 += w11 * (float)v[2]; a3 += w11 * (float)v[3];
            }
        }
    }
    bf16x4 o;
    o[0] = (bf16_t)a0; o[1] = (bf16_t)a1; o[2] = (bf16_t)a2; o[3] = (bf16_t)a3;
    *(bf16x4*)&out[(size_t)t * 256 + ch] = o;
}

// ============================ residual + LayerNorm (dual f32 + bf16 out) ============================
__global__ __launch_bounds__(256) void resid_ln_k(
    float* __restrict__ src, const float* __restrict__ r,
    const float* __restrict__ g, const float* __restrict__ b,
    bf16_t* __restrict__ src_bf)
{
    int l = blockIdx.x, tid = threadIdx.x;
    float v = src[(size_t)l * 256 + tid] + r[(size_t)l * 256 + tid];
    float a = v, s2 = v * v;
#pragma unroll
    for (int o = 32; o > 0; o >>= 1) { a += __shfl_down(a, o, 64); s2 += __shfl_down(s2, o, 64); }
    __shared__ float sh1[4], sh2[4], res[2];
    int lane = tid & 63, w = tid >> 6;
    if (lane == 0) { sh1[w] = a; sh2[w] = s2; }
    __syncthreads();
    if (tid == 0) {
        float A = sh1[0] + sh1[1] + sh1[2] + sh1[3];
        float B = sh2[0] + sh2[1] + sh2[2] + sh2[3];
        float mu = A * (1.f / 256.f);
        res[0] = mu;
        res[1] = rsqrtf(B * (1.f / 256.f) - mu * mu + 1e-5f);
    }
    __syncthreads();
    float o = (v - res[0]) * res[1] * g[tid] + b[tid];
    src[(size_t)l * 256 + tid] = o;
    src_bf[(size_t)l * 256 + tid] = (bf16_t)o;
}

// ============================ transpose f32 (P,256) -> (256,P) ============================
__global__ __launch_bounds__(256) void transpose_k(const float* __restrict__ in,
                                                   float* __restrict__ out, int P)
{
    __shared__ float t[32][33];
    int p0 = blockIdx.x * 32, c0 = blockIdx.y * 32;
    int x = threadIdx.x & 31, y = threadIdx.x >> 5;
#pragma unroll
    for (int i = 0; i < 4; ++i) {
        int r = y + i * 8;
        t[r][x] = in[(size_t)(p0 + r) * 256 + c0 + x];
    }
    __syncthreads();
#pragma unroll
    for (int i = 0; i < 4; ++i) {
        int r = y + i * 8;
        out[(size_t)(c0 + r) * P + p0 + x] = t[x][r];
    }
}

// ============================ host launcher ============================
extern "C" void kernel_launch(void* const* d_in, const int* in_sizes, int n_in,
                              void* d_out, int out_size, void* d_ws, size_t ws_size,
                              hipStream_t stream) {
    const float* res2    = (const float*)d_in[0];
    const float* res3    = (const float*)d_in[1];
    const float* res4    = (const float*)d_in[2];
    const float* res5    = (const float*)d_in[3];
    const float* proj_w5 = (const float*)d_in[4];
    const float* proj_b5 = (const float*)d_in[5];
    const float* gn_g5   = (const float*)d_in[6];
    const float* gn_b5   = (const float*)d_in[7];
    const float* proj_w4 = (const float*)d_in[8];
    const float* proj_b4 = (const float*)d_in[9];
    const float* gn_g4   = (const float*)d_in[10];
    const float* gn_b4   = (const float*)d_in[11];
    const float* proj_w3 = (const float*)d_in[12];
    const float* proj_b3 = (const float*)d_in[13];
    const float* gn_g3   = (const float*)d_in[14];
    const float* gn_b3   = (const float*)d_in[15];
    const float* level_embed = (const float*)d_in[16];
    const float* enc_vw  = (const float*)d_in[17];
    const float* enc_vb  = (const float*)d_in[18];
    const float* enc_ow  = (const float*)d_in[19];
    const float* enc_ob  = (const float*)d_in[20];
    const float* enc_aw  = (const float*)d_in[21];
    const float* enc_ab  = (const float*)d_in[22];
    const float* enc_pw  = (const float*)d_in[23];
    const float* enc_pb  = (const float*)d_in[24];
    const float* enc_ln1g = (const float*)d_in[25];
    const float* enc_ln1b = (const float*)d_in[26];
    const float* enc_f1w = (const float*)d_in[27];
    const float* enc_f1b = (const float*)d_in[28];
    const float* enc_f2w = (const float*)d_in[29];
    const float* enc_f2b = (const float*)d_in[30];
    const float* enc_ln2g = (const float*)d_in[31];
    const float* enc_ln2b = (const float*)d_in[32];
    const float* lat_w   = (const float*)d_in[33];
    const float* lat_gn_g = (const float*)d_in[34];
    const float* lat_gn_b = (const float*)d_in[35];
    const float* out_w   = (const float*)d_in[36];
    const float* out_gn_g = (const float*)d_in[37];
    const float* out_gn_b = (const float*)d_in[38];
    const float* mask_w  = (const float*)d_in[39];
    const float* mask_b  = (const float*)d_in[40];

    char* wsb = (char*)d_ws;
    const int L = L_TOT;

    // ---- workspace layout (bytes) ----
    const size_t OFF_SRC   = 0;                  // f32 L*256
    const size_t OFF_POS   = 22020096;           // f32 L*256
    const size_t OFF_TMPF  = 44040192;           // f32 L*256 (gemm f32 outs)
    const size_t OFF_OFFS  = 66060288;           // f32 L*192
    const size_t OFF_ATTW  = 82575360;           // f32 L*96
    const size_t OFF_FFNH  = 90832896;           // bf16 L*1024 (also valbf alias)
    const size_t OFF_QBUF  = 134873088;          // bf16 L*256
    const size_t OFF_MSOUT = 145883136;          // bf16 L*256
    const size_t OFF_SRCBF = 156893184;          // bf16 L*256
    const size_t OFF_W     = 167903232;
    const size_t W_VW   = OFF_W;                 // 6*256*256 bf16
    const size_t W_OW   = W_VW + 786432;
    const size_t W_AW   = W_OW + 589824;
    const size_t W_PW   = W_AW + 294912;
    const size_t W_F1   = W_PW + 786432;
    const size_t W_F2   = W_F1 + 3145728;
    const size_t W_P5   = W_F2 + 3145728;
    const size_t W_P4   = W_P5 + 1048576;
    const size_t W_P3   = W_P4 + 524288;
    const size_t W_LAT  = W_P3 + 262144;
    const size_t W_OUTW = W_LAT + 131072;
    const size_t W_MASKW= W_OUTW + 1179648;
    const size_t OFF_IMG   = W_MASKW + 1179648;  // bf16 65536*256 (HWC)
    const size_t OFF_STATS = OFF_IMG + 33554432;

    float*  src    = (float*)(wsb + OFF_SRC);
    float*  pos    = (float*)(wsb + OFF_POS);
    float*  tmpf   = (float*)(wsb + OFF_TMPF);
    float*  offs   = (float*)(wsb + OFF_OFFS);
    float*  attw   = (float*)(wsb + OFF_ATTW);
    bf16_t* ffnh   = (bf16_t*)(wsb + OFF_FFNH);
    bf16_t* valbf  = (bf16_t*)(wsb + OFF_FFNH);   // alias: disjoint live ranges
    bf16_t* qbuf   = (bf16_t*)(wsb + OFF_QBUF);
    bf16_t* msout  = (bf16_t*)(wsb + OFF_MSOUT);
    bf16_t* src_bf = (bf16_t*)(wsb + OFF_SRCBF);
    bf16_t* img    = (bf16_t*)(wsb + OFF_IMG);
    float*  stats  = (float*)(wsb + OFF_STATS);

    // projections phase: resXT staged over (dead) ffnh
    bf16_t* res5T = (bf16_t*)(wsb + OFF_FFNH);
    bf16_t* res4T = (bf16_t*)(wsb + OFF_FFNH + 4194304);
    bf16_t* res3T = (bf16_t*)(wsb + OFF_FFNH + 12582912);
    // tail aliases
    float* big0 = (float*)(wsb + OFF_POS);    // 64 MB over pos..attw
    float* big1 = (float*)(wsb + OFF_FFNH);   // 64 MB over ffnh..src_bf
    bf16_t* res2T = (bf16_t*)(wsb + OFF_FFNH);// 32 MB, dead before big1 use

    hipMemsetAsync(stats, 0, 1280, stream);
    dim3 blk(256);

    // ---- weight conversions ----
    tconv_k<<<dim3(8, 8, 6),  blk, 0, stream>>>(enc_vw, (bf16_t*)(wsb + W_VW), 256, 256,  65536, 65536);
    tconv_k<<<dim3(6, 8, 6),  blk, 0, stream>>>(enc_ow, (bf16_t*)(wsb + W_OW), 256, 192,  49152, 49152);
    tconv_k<<<dim3(3, 8, 6),  blk, 0, stream>>>(enc_aw, (bf16_t*)(wsb + W_AW), 256, 96,   24576, 24576);
    tconv_k<<<dim3(8, 8, 6),  blk, 0, stream>>>(enc_pw, (bf16_t*)(wsb + W_PW), 256, 256,  65536, 65536);
    tconv_k<<<dim3(32, 8, 6), blk, 0, stream>>>(enc_f1w, (bf16_t*)(wsb + W_F1), 256, 1024, 262144, 262144);
    tconv_k<<<dim3(8, 32, 6), blk, 0, stream>>>(enc_f2w, (bf16_t*)(wsb + W_F2), 1024, 256, 262144, 262144);
    tconv_k<<<dim3(8, 64, 1), blk, 0, stream>>>(proj_w5, (bf16_t*)(wsb + W_P5), 2048, 256, 0, 0);
    tconv_k<<<dim3(8, 32, 1), blk, 0, stream>>>(proj_w4, (bf16_t*)(wsb + W_P4), 1024, 256, 0, 0);
    tconv_k<<<dim3(8, 16, 1), blk, 0, stream>>>(proj_w3, (bf16_t*)(wsb + W_P3), 512, 256, 0, 0);
    tconv_k<<<dim3(8, 8, 1),  blk, 0, stream>>>(lat_w,   (bf16_t*)(wsb + W_LAT), 256, 256, 0, 0);
    wreorder_k<<<2304, blk, 0, stream>>>(out_w,  (bf16_t*)(wsb + W_OUTW));
    wreorder_k<<<2304, blk, 0, stream>>>(mask_w, (bf16_t*)(wsb + W_MASKW));
    // image transposes: f32 [C][HW] -> bf16 [HW][C]
    tconv_k<<<dim3(32, 64, 1),  blk, 0, stream>>>(res5, res5T, 2048, 1024, 0, 0);
    tconv_k<<<dim3(128, 32, 1), blk, 0, stream>>>(res4, res4T, 1024, 4096, 0, 0);
    tconv_k<<<dim3(512, 16, 1), blk, 0, stream>>>(res3, res3T, 512, 16384, 0, 0);

    // ---- level projections + GroupNorm ----
    gemm_bf_k<0,false,false,true,false><<<dim3(2, 8), blk, 0, stream>>>(
        res5T, (bf16_t*)(wsb + W_P5), proj_b5, src, nullptr, 1024, 256, 2048);
    gemm_bf_k<0,false,false,true,false><<<dim3(2, 32), blk, 0, stream>>>(
        res4T, (bf16_t*)(wsb + W_P4), proj_b4, src + (size_t)1024 * 256, nullptr, 4096, 256, 1024);
    gemm_bf_k<0,false,false,true,false><<<dim3(2, 128), blk, 0, stream>>>(
        res3T, (bf16_t*)(wsb + W_P3), proj_b3, src + (size_t)5120 * 256, nullptr, 16384, 256, 512);

    gn_stats_k<<<dim3(32, 4), blk, 0, stream>>>(src, 1024, stats + 0);
    gn_stats_k<<<dim3(32, 8), blk, 0, stream>>>(src + (size_t)1024 * 256, 4096, stats + 64);
    gn_stats_k<<<dim3(32, 16), blk, 0, stream>>>(src + (size_t)5120 * 256, 16384, stats + 128);
    gn_apply_k<false><<<1024, blk, 0, stream>>>(src, 1024, stats + 0, gn_g5, gn_b5);
    gn_apply_k<false><<<4096, blk, 0, stream>>>(src + (size_t)1024 * 256, 4096, stats + 64, gn_g4, gn_b4);
    gn_apply_k<false><<<16384, blk, 0, stream>>>(src + (size_t)5120 * 256, 16384, stats + 128, gn_g3, gn_b3);

    cvt_k<<<L, blk, 0, stream>>>(src, src_bf, L * 256);
    pos_embed_k<<<L, blk, 0, stream>>>(pos, level_embed);

    // ---- encoder layers ----
    for (int i = 0; i < 6; ++i) {
        const bf16_t* vwT = (bf16_t*)(wsb + W_VW) + (size_t)i * 65536;
        const bf16_t* owT = (bf16_t*)(wsb + W_OW) + (size_t)i * 49152;
        const bf16_t* awT = (bf16_t*)(wsb + W_AW) + (size_t)i * 24576;
        const bf16_t* pwT = (bf16_t*)(wsb + W_PW) + (size_t)i * 65536;
        const bf16_t* f1T = (bf16_t*)(wsb + W_F1) + (size_t)i * 262144;
        const bf16_t* f2T = (bf16_t*)(wsb + W_F2) + (size_t)i * 262144;
        const float* vb = enc_vb + (size_t)i * 256;
        const float* ob = enc_ob + (size_t)i * 192;
        const float* ab = enc_ab + (size_t)i * 96;
        const float* pb = enc_pb + (size_t)i * 256;
        const float* l1g = enc_ln1g + (size_t)i * 256;
        const float* l1b = enc_ln1b + (size_t)i * 256;
        const float* f1b = enc_f1b + (size_t)i * 1024;
        const float* f2b = enc_f2b + (size_t)i * 256;
        const float* l2g = enc_ln2g + (size_t)i * 256;
        const float* l2b = enc_ln2b + (size_t)i * 256;

        add_k<<<L, blk, 0, stream>>>(src, pos, qbuf, L * 256);
        gemm_bf_k<0,false,false,false,true><<<dim3(2, 168), blk, 0, stream>>>(
            src_bf, vwT, vb, nullptr, valbf, L, 256, 256);
        gemm_bf_k<0,true,false,true,false><<<dim3(2, 168), blk, 0, stream>>>(
            qbuf, owT, ob, offs, nullptr, L, 192, 256);
        gemm_bf_k<0,true,false,true,false><<<dim3(1, 168), blk, 0, stream>>>(
            qbuf, awT, ab, attw, nullptr, L, 96, 256);
        softmax12_k<<<(L * 8 + 255) / 256, blk, 0, stream>>>(attw, L * 8);
        msdeform_k<<<L / 4, blk, 0, stream>>>(valbf, offs, attw, msout);
        gemm_bf_k<0,false,false,true,false><<<dim3(2, 168), blk, 0, stream>>>(
            msout, pwT, pb, tmpf, nullptr, L, 256, 256);
        resid_ln_k<<<L, blk, 0, stream>>>(src, tmpf, l1g, l1b, src_bf);
        gemm_bf_k<0,false,true,false,true><<<dim3(8, 168), blk, 0, stream>>>(
            src_bf, f1T, f1b, nullptr, ffnh, L, 1024, 256);
        gemm_bf_k<0,false,false,true,false><<<dim3(2, 168), blk, 0, stream>>>(
            ffnh, f2T, f2b, tmpf, nullptr, L, 256, 1024);
        resid_ln_k<<<L, blk, 0, stream>>>(src, tmpf, l2g, l2b, src_bf);
    }

    // ---- decoder tail ----
    tconv_k<<<dim3(2048, 8, 1), blk, 0, stream>>>(res2, res2T, 256, 65536, 0, 0);
    gemm_bf_k<0,false,false,true,false><<<dim3(2, 512), blk, 0, stream>>>(
        res2T, (bf16_t*)(wsb + W_LAT), nullptr, big0, nullptr, 65536, 256, 256);
    gn_stats_k<<<dim3(32, 32), blk, 0, stream>>>(big0, 65536, stats + 192);
    // fused GN + upsample-add + cvt -> img (bf16 HWC)
    gn_up_cvt_k<<<65536, blk, 0, stream>>>(big0, stats + 192, lat_gn_g, lat_gn_b,
                                           src + (size_t)5120 * 256, img);

    // conv1 (out_w, no bias): implicit im2col on bf16 HWC image
    gemm_bf_k<2,false,false,true,false><<<dim3(2, 512), blk, 0, stream>>>(
        img, (bf16_t*)(wsb + W_OUTW), nullptr, big1, nullptr, 65536, 256, 2304);
    gn_stats_k<<<dim3(32, 32), blk, 0, stream>>>(big1, 65536, stats + 256);
    gn_relu_cvt_k<<<65536, blk, 0, stream>>>(big1, stats + 256, out_gn_g, out_gn_b, img);

    // conv2 (mask_w + bias)
    gemm_bf_k<2,false,false,true,false><<<dim3(2, 512), blk, 0, stream>>>(
        img, (bf16_t*)(wsb + W_MASKW), mask_b, big0, nullptr, 65536, 256, 2304);

    transpose_k<<<dim3(2048, 8), blk, 0, stream>>>(big0, (float*)d_out, 65536);
}